// Round 10
// baseline (193.083 us; speedup 1.0000x reference)
//
#include <hip/hip_runtime.h>
#include <hip/hip_bf16.h>

#define Tsz 2048
#define Csz 1024
#define Hn 16

typedef short s8v __attribute__((ext_vector_type(8)));
typedef short s4v __attribute__((ext_vector_type(4)));
typedef float f4v __attribute__((ext_vector_type(4)));
typedef int   i4v __attribute__((ext_vector_type(4)));
typedef unsigned u2v __attribute__((ext_vector_type(2)));

#define QSCALE (0.125f * 1.44269504088896f)  // 1/sqrt(64) * log2(e), folded into Q

// fast bf16 round (bits+0x8000)>>16 : 2 VALU vs ~6 for software RNE
__device__ __forceinline__ unsigned short bfr(float x) {
    return (unsigned short)((__builtin_bit_cast(unsigned, x) + 0x8000u) >> 16);
}
__device__ __forceinline__ unsigned pack2_rn(float a, float b) {
    const unsigned ua = __builtin_bit_cast(unsigned, a) + 0x8000u;
    const unsigned ub = __builtin_bit_cast(unsigned, b) + 0x8000u;
    return (ua >> 16) | (ub & 0xFFFF0000u);
}
// v_cvt_pk_bf16_f32 via HIP conversion (compiler emits the packed cvt; a->low, b->high)
// NOTE: __hip_bfloat162 is not trivially copyable in this ROCm -> memcpy, not bit_cast.
__device__ __forceinline__ unsigned cvt2(float a, float b) {
    __hip_bfloat162 h = __float22bfloat162_rn(float2{a, b});
    unsigned r;
    __builtin_memcpy(&r, &h, 4);
    return r;
}

__device__ __forceinline__ void gload_lds(const void* g, void* l) {
    __builtin_amdgcn_global_load_lds(
        (const __attribute__((address_space(1))) void*)g,
        (__attribute__((address_space(3))) void*)l, 16, 0, 0);
}

// ---------------- fp32 -> bf16 conversion, exact-size grid (8192 blocks) ----------------
__global__ void cvt6(const float* __restrict__ x, const float* __restrict__ wq,
                     const float* __restrict__ wk, const float* __restrict__ wv,
                     const float* __restrict__ wp,
                     short* __restrict__ xo, short* __restrict__ qo,
                     short* __restrict__ ko, short* __restrict__ vo,
                     short* __restrict__ po) {
    const int bx = blockIdx.x;
    const float* in; short* out; int ib;
    if (bx < 4096) { in = x; out = xo; ib = bx; }
    else {
        const int r = bx - 4096, w = r >> 10;
        ib = r & 1023;
        switch (w) {
            case 0: in = wq; out = qo; break;
            case 1: in = wk; out = ko; break;
            case 2: in = wv; out = vo; break;
            default: in = wp; out = po; break;
        }
    }
    const int i = ib * 1024 + threadIdx.x * 4;
    float4 v = *(const float4*)(in + i);
    int2 o;
    o.x = (int)pack2_rn(v.x, v.y);
    o.y = (int)pack2_rn(v.z, v.w);
    *(int2*)(out + i) = o;
}

// ---------------- fused QKV GEMM (m97 structure) ----------------
__global__ __launch_bounds__(256, 3) void qkv_gemm(
    const short* __restrict__ X,
    const short* __restrict__ Wq, const short* __restrict__ Wk, const short* __restrict__ Wv,
    const float* __restrict__ bq, const float* __restrict__ bk, const float* __restrict__ bv,
    short* __restrict__ Qo, short* __restrict__ Ko, short* __restrict__ Vto)
{
    const int z = blockIdx.z;
    const short* W = (z == 0) ? Wq : (z == 1) ? Wk : Wv;
    const float* bias = (z == 0) ? bq : (z == 1) ? bk : bv;

    __shared__ __align__(16) short Ash[128 * 32];
    __shared__ __align__(16) short Bsh[128 * 32];
    __shared__ __align__(16) short TR[64 * 72];   // transpose staging (z==2 epilogue)

    const int tid = threadIdx.x, lane = tid & 63, wave = tid >> 6;
    const int ln = lane & 15, hi = lane >> 4;
    const int m0 = blockIdx.x * 128, n0 = blockIdx.y * 128;
    const int wm = (wave >> 1) * 64, wn = (wave & 1) * 64;

    const short* Ag = X + (size_t)(m0 + (tid >> 2)) * Csz + (tid & 3) * 8;
    const short* Bg = W + (size_t)(n0 + (tid >> 2)) * Csz + (tid & 3) * 8;

    f4v acc[4][4];
    #pragma unroll
    for (int mt = 0; mt < 4; mt++)
        #pragma unroll
        for (int nt = 0; nt < 4; nt++)
            #pragma unroll
            for (int i = 0; i < 4; i++) acc[mt][nt][i] = 0.f;

    for (int k0 = 0; k0 < Csz; k0 += 32) {
        __syncthreads();
        gload_lds(Ag + k0, Ash + tid * 8);
        gload_lds(Ag + k0 + (size_t)64 * Csz, Ash + 2048 + tid * 8);
        gload_lds(Bg + k0, Bsh + tid * 8);
        gload_lds(Bg + k0 + (size_t)64 * Csz, Bsh + 2048 + tid * 8);
        __syncthreads();

        s8v af[4], bfr_[4];
        #pragma unroll
        for (int mt = 0; mt < 4; mt++)
            af[mt] = *(const s8v*)(Ash + (wm + mt * 16 + ln) * 32 + hi * 8);
        #pragma unroll
        for (int nt = 0; nt < 4; nt++)
            bfr_[nt] = *(const s8v*)(Bsh + (wn + nt * 16 + ln) * 32 + hi * 8);
        #pragma unroll
        for (int mt = 0; mt < 4; mt++)
            #pragma unroll
            for (int nt = 0; nt < 4; nt++)
                acc[mt][nt] = __builtin_amdgcn_mfma_f32_16x16x32_bf16(af[mt], bfr_[nt], acc[mt][nt], 0, 0, 0);
    }

    if (z == 2) {
        const int b = m0 >> 11, t0 = m0 & 2047;
        float bvv[4];
        #pragma unroll
        for (int nt = 0; nt < 4; nt++) bvv[nt] = bias[n0 + wn + nt * 16 + ln];
        #pragma unroll
        for (int ph = 0; ph < 4; ph++) {
            const int mh = ph >> 1, nh = ph & 1;
            __syncthreads();
            if ((wave >> 1) == mh && (wave & 1) == nh) {
                #pragma unroll
                for (int mt = 0; mt < 4; mt++)
                    #pragma unroll
                    for (int nt = 0; nt < 4; nt++) {
                        int2 pk;
                        pk.x = (int)pack2_rn(acc[mt][nt][0] + bvv[nt], acc[mt][nt][1] + bvv[nt]);
                        pk.y = (int)pack2_rn(acc[mt][nt][2] + bvv[nt], acc[mt][nt][3] + bvv[nt]);
                        *(int2*)(TR + (nt * 16 + ln) * 72 + mt * 16 + hi * 4) = pk;
                    }
            }
            __syncthreads();
            const int chl = tid >> 2, seg = tid & 3;
            const s8v r0 = *(const s8v*)(TR + chl * 72 + seg * 16);
            const s8v r1 = *(const s8v*)(TR + chl * 72 + seg * 16 + 8);
            short* dst = Vto + (size_t)(b * 1024 + n0 + nh * 64 + chl) * Tsz + t0 + mh * 64 + seg * 16;
            *(s8v*)(dst) = r0;
            *(s8v*)(dst + 8) = r1;
        }
        return;
    }

    const float scale = (z == 0) ? QSCALE : 1.0f;
    short* out = (z == 0) ? Qo : Ko;

    #pragma unroll
    for (int nt = 0; nt < 4; nt++) {
        const int col = n0 + wn + nt * 16 + ln;
        const float bvv = bias[col];
        #pragma unroll
        for (int mt = 0; mt < 4; mt++) {
            const int row0 = m0 + wm + mt * 16 + hi * 4;
            #pragma unroll
            for (int i = 0; i < 4; i++)
                out[(size_t)(row0 + i) * Csz + col] = (short)bfr((acc[mt][nt][i] + bvv) * scale);
        }
    }
}

// ---------------- output projection GEMM (f32 out), 128x64 tiles, grid (32,16) ----------------
__global__ __launch_bounds__(256, 2) void proj_gemm(
    const short* __restrict__ A, const short* __restrict__ W,
    const float* __restrict__ bias, float* __restrict__ out)
{
    __shared__ __align__(16) short Ash[128 * 32];
    __shared__ __align__(16) short Bsh[64 * 32];

    const int tid = threadIdx.x, lane = tid & 63, wave = tid >> 6;
    const int ln = lane & 15, hi = lane >> 4;
    const int m0 = blockIdx.x * 128, n0 = blockIdx.y * 64;
    const int wm = (wave >> 1) * 64, wn = (wave & 1) * 32;

    const short* Ag = A + (size_t)(m0 + (tid >> 2)) * Csz + (tid & 3) * 8;
    const short* Bg = W + (size_t)(n0 + (tid >> 2)) * Csz + (tid & 3) * 8;

    f4v acc[4][2];
    #pragma unroll
    for (int mt = 0; mt < 4; mt++)
        #pragma unroll
        for (int nt = 0; nt < 2; nt++)
            #pragma unroll
            for (int i = 0; i < 4; i++) acc[mt][nt][i] = 0.f;

    for (int k0 = 0; k0 < Csz; k0 += 32) {
        __syncthreads();
        gload_lds(Ag + k0, Ash + tid * 8);
        gload_lds(Ag + k0 + (size_t)64 * Csz, Ash + 2048 + tid * 8);
        gload_lds(Bg + k0, Bsh + tid * 8);
        __syncthreads();

        s8v af[4], bfr_[2];
        #pragma unroll
        for (int mt = 0; mt < 4; mt++)
            af[mt] = *(const s8v*)(Ash + (wm + mt * 16 + ln) * 32 + hi * 8);
        #pragma unroll
        for (int nt = 0; nt < 2; nt++)
            bfr_[nt] = *(const s8v*)(Bsh + (wn + nt * 16 + ln) * 32 + hi * 8);
        #pragma unroll
        for (int mt = 0; mt < 4; mt++)
            #pragma unroll
            for (int nt = 0; nt < 2; nt++)
                acc[mt][nt] = __builtin_amdgcn_mfma_f32_16x16x32_bf16(af[mt], bfr_[nt], acc[mt][nt], 0, 0, 0);
    }

    #pragma unroll
    for (int nt = 0; nt < 2; nt++) {
        const int col = n0 + wn + nt * 16 + ln;
        const float bvv = bias[col];
        #pragma unroll
        for (int mt = 0; mt < 4; mt++)
            #pragma unroll
            for (int i = 0; i < 4; i++)
                out[(size_t)(m0 + wm + mt * 16 + hi * 4 + i) * Csz + col] = acc[mt][nt][i] + bvv;
    }
}

// ---------------- Flash attention v18: 4 q-tiles per block + XCD-affinity mapping ----------------
// Confirmed model (v16/v17): t = 18.5us + 1.88ns * block-iterations. This round:
//  (1) 4 q-tiles per block {t, 15-t, 16+t, 31-t} (one per causal quartile ->
//      every block does exactly 66 q-tile-units): iterations 12544 -> 7296.
//      256 blocks x 256 thr; per-bh coverage is a bijection over qt 0..31.
//  (2) XCD-affinity: blocks sharing a head (bh) get equal blockIdx%8 so the
//      8 same-bh blocks land on ONE XCD's L2 (K/V stream fetched once/XCD).
//      decode: xcd=n&7; r=n>>3; t=r&7; bh=((r>>3)<<3)|xcd.
// Compute core byte-identical to v16/v17 (permlane P, swizzle, MFMA l-sum, cvt2).
__global__ __launch_bounds__(256, 1) void attn18(
    const short* __restrict__ Q, const short* __restrict__ Kg,
    const short* __restrict__ Vt, short* __restrict__ Y)
{
    __shared__ __align__(16) short SB[2][2][64 * 64];   // [buf][K/V][row][swizzled 16B slots]

    const int tid = threadIdx.x, lane = tid & 63, wave = tid >> 6;
    const int ln = lane & 15, hi = lane >> 4;

    const int n = blockIdx.x;
    const int xcd = n & 7, r = n >> 3;
    const int t = r & 7;                              // 0..7
    const int bh = ((r >> 3) << 3) | xcd;             // 0..31, same-bh -> same XCD slot
    const int qts_[4] = { t, 15 - t, 16 + t, 31 - t };
    const int nkb = 32 - t;                           // key-tiles (heaviest tile's need)

    const size_t base = (size_t)(bh >> 4) * Tsz * Csz + (size_t)(bh & 15) * 64;
    const size_t vtbase = (size_t)bh * 64 * Tsz;
    const int qrel = wave * 16 + ln;                  // within-tile q row (MFMA n-col)

    s8v qf[4][2];
    #pragma unroll
    for (int tt = 0; tt < 4; tt++)
        #pragma unroll
        for (int kk = 0; kk < 2; kk++)
            qf[tt][kk] = *(const s8v*)(Q + base + (size_t)(qts_[tt] * 64 + qrel) * Csz + kk * 32 + hi * 8);

    f4v o[4][4];
    f4v lacc[4];
    #pragma unroll
    for (int tt = 0; tt < 4; tt++) {
        #pragma unroll
        for (int i = 0; i < 4; i++) lacc[tt][i] = 0.f;
        #pragma unroll
        for (int dt = 0; dt < 4; dt++)
            #pragma unroll
            for (int i = 0; i < 4; i++) o[tt][dt][i] = 0.f;
    }

    const s8v ones8 = { (short)0x3F80, (short)0x3F80, (short)0x3F80, (short)0x3F80,
                        (short)0x3F80, (short)0x3F80, (short)0x3F80, (short)0x3F80 };

    // DMA staging: thread covers rows sr / sr+32, LDS slot scs (linear dest tid*16B);
    // global col-slot pre-swizzled: scs ^ (sr&7). (sr+32)&7 == sr&7.
    const int sr = tid >> 3, scs = tid & 7;
    const int csw = (scs ^ (sr & 7)) * 8;             // pre-swizzled col offset (shorts)
    const short* KsA = Kg + base + (size_t)sr * Csz + csw;
    const short* KsB = KsA + (size_t)32 * Csz;
    const short* VsA = Vt + vtbase + (size_t)sr * Tsz + csw;
    const short* VsB = VsA + (size_t)32 * Tsz;

    // fragment-read offsets (row = nt*16+ln, slot = kk*4+hi, swizzle by ln&7) — green
    int foff[2][4];
    #pragma unroll
    for (int nt = 0; nt < 4; nt++)
        #pragma unroll
        for (int kk = 0; kk < 2; kk++)
            foff[kk][nt] = (nt * 16 + ln) * 64 + (((kk * 4 + hi) ^ (ln & 7)) * 8);

    #define STAGE(B, kb_) {                                      \
        const size_t ko_ = (size_t)(kb_) * 64;                   \
        gload_lds(KsA + ko_ * Csz, &SB[B][0][tid * 8]);          \
        gload_lds(KsB + ko_ * Csz, &SB[B][0][2048 + tid * 8]);   \
        gload_lds(VsA + ko_,       &SB[B][1][tid * 8]);          \
        gload_lds(VsB + ko_,       &SB[B][1][2048 + tid * 8]);   \
    }

    // prologue: tile 0 -> buf 0 (also drains qf loads)
    STAGE(0, 0);
    asm volatile("s_waitcnt vmcnt(0)" ::: "memory");
    __builtin_amdgcn_s_barrier();

    // one key-tile with compile-time buffer index B0; stage next into B1
    #define TILE(B0, B1, kb_) {                                                     \
        const bool st_ = (kb_) + 1 < nkb;                                           \
        if (st_) STAGE(B1, (kb_) + 1);                                              \
        s8v kf[2][4], vf[2][4];                                                     \
        for (int nt = 0; nt < 4; nt++) {                                            \
            kf[0][nt] = *(const s8v*)(&SB[B0][0][foff[0][nt]]);                     \
            kf[1][nt] = *(const s8v*)(&SB[B0][0][foff[1][nt]]);                     \
            vf[0][nt] = *(const s8v*)(&SB[B0][1][foff[0][nt]]);                     \
            vf[1][nt] = *(const s8v*)(&SB[B0][1][foff[1][nt]]);                     \
        }                                                                           \
        _Pragma("unroll")                                                           \
        for (int tt = 0; tt < 4; tt++) {                                            \
            if ((kb_) > qts_[tt]) continue;          /* wave-uniform */             \
            f4v s[4];                                                               \
            for (int nt = 0; nt < 4; nt++) {                                        \
                for (int i = 0; i < 4; i++) s[nt][i] = 0.f;                         \
                s[nt] = __builtin_amdgcn_mfma_f32_16x16x32_bf16(kf[0][nt], qf[tt][0], s[nt], 0, 0, 0); \
                s[nt] = __builtin_amdgcn_mfma_f32_16x16x32_bf16(kf[1][nt], qf[tt][1], s[nt], 0, 0, 0); \
            }                                                                       \
            const bool dg_ = ((kb_) == qts_[tt]);                                   \
            unsigned pw[4][2];                                                      \
            for (int nt = 0; nt < 4; nt++) {                                        \
                float e0 = exp2f(s[nt][0]), e1 = exp2f(s[nt][1]);                   \
                float e2 = exp2f(s[nt][2]), e3 = exp2f(s[nt][3]);                   \
                if (dg_) {                                                          \
                    const int kr = nt * 16 + hi * 4;                                \
                    if (kr + 0 > qrel) e0 = 0.f;                                    \
                    if (kr + 1 > qrel) e1 = 0.f;                                    \
                    if (kr + 2 > qrel) e2 = 0.f;                                    \
                    if (kr + 3 > qrel) e3 = 0.f;                                    \
                }                                                                   \
                pw[nt][0] = cvt2(e0, e1);                                           \
                pw[nt][1] = cvt2(e2, e3);                                           \
            }                                                                       \
            u2v r0a = __builtin_amdgcn_permlane32_swap(pw[0][0], pw[1][0], false, false); \
            u2v r0b = __builtin_amdgcn_permlane16_swap(r0a[0], r0a[1], false, false); \
            u2v r1a = __builtin_amdgcn_permlane32_swap(pw[0][1], pw[1][1], false, false); \
            u2v r1b = __builtin_amdgcn_permlane16_swap(r1a[0], r1a[1], false, false); \
            u2v r2a = __builtin_amdgcn_permlane32_swap(pw[2][0], pw[3][0], false, false); \
            u2v r2b = __builtin_amdgcn_permlane16_swap(r2a[0], r2a[1], false, false); \
            u2v r3a = __builtin_amdgcn_permlane32_swap(pw[2][1], pw[3][1], false, false); \
            u2v r3b = __builtin_amdgcn_permlane16_swap(r3a[0], r3a[1], false, false); \
            i4v p0 = { (int)r0b[0], (int)r1b[0], (int)r0b[1], (int)r1b[1] };        \
            i4v p1 = { (int)r2b[0], (int)r3b[0], (int)r2b[1], (int)r3b[1] };        \
            const s8v pb0 = __builtin_bit_cast(s8v, p0);                            \
            const s8v pb1 = __builtin_bit_cast(s8v, p1);                            \
            for (int dt = 0; dt < 4; dt++) {                                        \
                o[tt][dt] = __builtin_amdgcn_mfma_f32_16x16x32_bf16(vf[0][dt], pb0, o[tt][dt], 0, 0, 0); \
                o[tt][dt] = __builtin_amdgcn_mfma_f32_16x16x32_bf16(vf[1][dt], pb1, o[tt][dt], 0, 0, 0); \
            }                                                                       \
            lacc[tt] = __builtin_amdgcn_mfma_f32_16x16x32_bf16(ones8, pb0, lacc[tt], 0, 0, 0); \
            lacc[tt] = __builtin_amdgcn_mfma_f32_16x16x32_bf16(ones8, pb1, lacc[tt], 0, 0, 0); \
        }                                                                           \
        if (st_) {                                                                  \
            asm volatile("s_waitcnt vmcnt(0)" ::: "memory");                        \
            __builtin_amdgcn_s_barrier();                                           \
        }                                                                           \
    }

    for (int kb = 0; kb < nkb; kb += 2) {
        TILE(0, 1, kb);
        if (kb + 1 < nkb) TILE(1, 0, kb + 1);
    }
    #undef TILE
    #undef STAGE

    // l for q=ln is fully reduced in every lane's lacc[tt] (ones-MFMA over all keys)
    #pragma unroll
    for (int tt = 0; tt < 4; tt++) {
        const float inv = 1.0f / lacc[tt][0];
        const int qrow = qts_[tt] * 64 + qrel;
        #pragma unroll
        for (int dt = 0; dt < 4; dt++) {
            int2 w;
            w.x = (int)cvt2(o[tt][dt][0] * inv, o[tt][dt][1] * inv);
            w.y = (int)cvt2(o[tt][dt][2] * inv, o[tt][dt][3] * inv);
            *(int2*)(Y + base + (size_t)qrow * Csz + dt * 16 + hi * 4) = w;
        }
    }
}

extern "C" void kernel_launch(void* const* d_in, const int* in_sizes, int n_in,
                              void* d_out, int out_size, void* d_ws, size_t ws_size,
                              hipStream_t stream) {
    const float* x  = (const float*)d_in[0];
    const float* Wq = (const float*)d_in[1];
    const float* bq = (const float*)d_in[2];
    const float* Wk = (const float*)d_in[3];
    const float* bk = (const float*)d_in[4];
    const float* Wv = (const float*)d_in[5];
    const float* bv = (const float*)d_in[6];
    const float* Wp = (const float*)d_in[7];
    const float* bp = (const float*)d_in[8];

    char* ws = (char*)d_ws;
    short* Xb  = (short*)(ws);                 // 8 MB
    short* Wqb = (short*)(ws + (8u  << 20));   // 2 MB each
    short* Wkb = (short*)(ws + (10u << 20));
    short* Wvb = (short*)(ws + (12u << 20));
    short* Wpb = (short*)(ws + (14u << 20));
    short* Qb  = (short*)(ws + (16u << 20));   // 8 MB each
    short* Kb  = (short*)(ws + (24u << 20));
    short* Vtb = (short*)(ws + (32u << 20));   // V transposed per head [B*H*64, T]
    short* Yb  = (short*)(ws + (40u << 20));

    hipLaunchKernelGGL(cvt6, dim3(8192), dim3(256), 0, stream,
                       x, Wq, Wk, Wv, Wp, Xb, Wqb, Wkb, Wvb, Wpb);

    hipLaunchKernelGGL(qkv_gemm, dim3(32, 8, 3), dim3(256), 0, stream,
                       Xb, Wqb, Wkb, Wvb, bq, bk, bv, Qb, Kb, Vtb);

    hipLaunchKernelGGL(attn18, dim3(256), dim3(256), 0, stream, Qb, Kb, Vtb, Yb);

    hipLaunchKernelGGL(proj_gemm, dim3(32, 16), dim3(256), 0, stream, Yb, Wpb, bp, (float*)d_out);
}

// Round 11
// 185.546 us; speedup vs baseline: 1.0406x; 1.0406x over previous
//
#include <hip/hip_runtime.h>
#include <hip/hip_bf16.h>

#define Tsz 2048
#define Csz 1024
#define Hn 16

typedef short s8v __attribute__((ext_vector_type(8)));
typedef short s4v __attribute__((ext_vector_type(4)));
typedef float f4v __attribute__((ext_vector_type(4)));
typedef int   i4v __attribute__((ext_vector_type(4)));
typedef unsigned u2v __attribute__((ext_vector_type(2)));

#define QSCALE (0.125f * 1.44269504088896f)  // 1/sqrt(64) * log2(e), folded into Q

// fast bf16 round (bits+0x8000)>>16 : 2 VALU vs ~6 for software RNE
__device__ __forceinline__ unsigned short bfr(float x) {
    return (unsigned short)((__builtin_bit_cast(unsigned, x) + 0x8000u) >> 16);
}
__device__ __forceinline__ unsigned pack2_rn(float a, float b) {
    const unsigned ua = __builtin_bit_cast(unsigned, a) + 0x8000u;
    const unsigned ub = __builtin_bit_cast(unsigned, b) + 0x8000u;
    return (ua >> 16) | (ub & 0xFFFF0000u);
}
// v_cvt_pk_bf16_f32 via HIP conversion (compiler emits the packed cvt; a->low, b->high)
// NOTE: __hip_bfloat162 is not trivially copyable in this ROCm -> memcpy, not bit_cast.
__device__ __forceinline__ unsigned cvt2(float a, float b) {
    __hip_bfloat162 h = __float22bfloat162_rn(float2{a, b});
    unsigned r;
    __builtin_memcpy(&r, &h, 4);
    return r;
}

__device__ __forceinline__ void gload_lds(const void* g, void* l) {
    __builtin_amdgcn_global_load_lds(
        (const __attribute__((address_space(1))) void*)g,
        (__attribute__((address_space(3))) void*)l, 16, 0, 0);
}

// ---------------- fp32 -> bf16 conversion, exact-size grid (8192 blocks) ----------------
__global__ void cvt6(const float* __restrict__ x, const float* __restrict__ wq,
                     const float* __restrict__ wk, const float* __restrict__ wv,
                     const float* __restrict__ wp,
                     short* __restrict__ xo, short* __restrict__ qo,
                     short* __restrict__ ko, short* __restrict__ vo,
                     short* __restrict__ po) {
    const int bx = blockIdx.x;
    const float* in; short* out; int ib;
    if (bx < 4096) { in = x; out = xo; ib = bx; }
    else {
        const int r = bx - 4096, w = r >> 10;
        ib = r & 1023;
        switch (w) {
            case 0: in = wq; out = qo; break;
            case 1: in = wk; out = ko; break;
            case 2: in = wv; out = vo; break;
            default: in = wp; out = po; break;
        }
    }
    const int i = ib * 1024 + threadIdx.x * 4;
    float4 v = *(const float4*)(in + i);
    int2 o;
    o.x = (int)pack2_rn(v.x, v.y);
    o.y = (int)pack2_rn(v.z, v.w);
    *(int2*)(out + i) = o;
}

// ---------------- fused QKV GEMM, v2: double-buffered issue-early/drain-late staging ----------------
// m97 structure, but the staging convoy is taken off the critical path: stage
// tile k+1 into buf^1 BEFORE computing tile k from buf; one vmcnt(0)+s_barrier
// per iteration (was: two __syncthreads with zero load/compute overlap).
// LDS: 2*(8+8)+9 = 41 KB -> still 3 blocks/CU at LB(256,3).
__global__ __launch_bounds__(256, 3) void qkv_gemm(
    const short* __restrict__ X,
    const short* __restrict__ Wq, const short* __restrict__ Wk, const short* __restrict__ Wv,
    const float* __restrict__ bq, const float* __restrict__ bk, const float* __restrict__ bv,
    short* __restrict__ Qo, short* __restrict__ Ko, short* __restrict__ Vto)
{
    const int z = blockIdx.z;
    const short* W = (z == 0) ? Wq : (z == 1) ? Wk : Wv;
    const float* bias = (z == 0) ? bq : (z == 1) ? bk : bv;

    __shared__ __align__(16) short Ash[2][128 * 32];
    __shared__ __align__(16) short Bsh[2][128 * 32];
    __shared__ __align__(16) short TR[64 * 72];   // transpose staging (z==2 epilogue)

    const int tid = threadIdx.x, lane = tid & 63, wave = tid >> 6;
    const int ln = lane & 15, hi = lane >> 4;
    const int m0 = blockIdx.x * 128, n0 = blockIdx.y * 128;
    const int wm = (wave >> 1) * 64, wn = (wave & 1) * 64;

    const short* Ag = X + (size_t)(m0 + (tid >> 2)) * Csz + (tid & 3) * 8;
    const short* Bg = W + (size_t)(n0 + (tid >> 2)) * Csz + (tid & 3) * 8;

    f4v acc[4][4];
    #pragma unroll
    for (int mt = 0; mt < 4; mt++)
        #pragma unroll
        for (int nt = 0; nt < 4; nt++)
            #pragma unroll
            for (int i = 0; i < 4; i++) acc[mt][nt][i] = 0.f;

    #define QSTAGE(B, k0_) {                                              \
        gload_lds(Ag + (k0_), Ash[B] + tid * 8);                          \
        gload_lds(Ag + (k0_) + (size_t)64 * Csz, Ash[B] + 2048 + tid * 8);\
        gload_lds(Bg + (k0_), Bsh[B] + tid * 8);                          \
        gload_lds(Bg + (k0_) + (size_t)64 * Csz, Bsh[B] + 2048 + tid * 8);\
    }

    QSTAGE(0, 0);
    asm volatile("s_waitcnt vmcnt(0)" ::: "memory");
    __builtin_amdgcn_s_barrier();

    #define QTILE(B, k0_) {                                                         \
        const bool more_ = (k0_) + 32 < Csz;                                        \
        if (more_) QSTAGE(B ^ 1, (k0_) + 32);                                       \
        s8v af[4], bf_[4];                                                          \
        for (int mt = 0; mt < 4; mt++)                                              \
            af[mt] = *(const s8v*)(Ash[B] + (wm + mt * 16 + ln) * 32 + hi * 8);     \
        for (int nt = 0; nt < 4; nt++)                                              \
            bf_[nt] = *(const s8v*)(Bsh[B] + (wn + nt * 16 + ln) * 32 + hi * 8);    \
        for (int mt = 0; mt < 4; mt++)                                              \
            for (int nt = 0; nt < 4; nt++)                                          \
                acc[mt][nt] = __builtin_amdgcn_mfma_f32_16x16x32_bf16(af[mt], bf_[nt], acc[mt][nt], 0, 0, 0); \
        if (more_) {                                                                \
            asm volatile("s_waitcnt vmcnt(0)" ::: "memory");                        \
            __builtin_amdgcn_s_barrier();                                           \
        }                                                                           \
    }

    for (int k0 = 0; k0 < Csz; k0 += 64) {
        QTILE(0, k0);
        QTILE(1, k0 + 32);
    }
    #undef QTILE
    #undef QSTAGE

    if (z == 2) {
        const int b = m0 >> 11, t0 = m0 & 2047;
        float bvv[4];
        #pragma unroll
        for (int nt = 0; nt < 4; nt++) bvv[nt] = bias[n0 + wn + nt * 16 + ln];
        #pragma unroll
        for (int ph = 0; ph < 4; ph++) {
            const int mh = ph >> 1, nh = ph & 1;
            __syncthreads();
            if ((wave >> 1) == mh && (wave & 1) == nh) {
                #pragma unroll
                for (int mt = 0; mt < 4; mt++)
                    #pragma unroll
                    for (int nt = 0; nt < 4; nt++) {
                        int2 pk;
                        pk.x = (int)pack2_rn(acc[mt][nt][0] + bvv[nt], acc[mt][nt][1] + bvv[nt]);
                        pk.y = (int)pack2_rn(acc[mt][nt][2] + bvv[nt], acc[mt][nt][3] + bvv[nt]);
                        *(int2*)(TR + (nt * 16 + ln) * 72 + mt * 16 + hi * 4) = pk;
                    }
            }
            __syncthreads();
            const int chl = tid >> 2, seg = tid & 3;
            const s8v r0 = *(const s8v*)(TR + chl * 72 + seg * 16);
            const s8v r1 = *(const s8v*)(TR + chl * 72 + seg * 16 + 8);
            short* dst = Vto + (size_t)(b * 1024 + n0 + nh * 64 + chl) * Tsz + t0 + mh * 64 + seg * 16;
            *(s8v*)(dst) = r0;
            *(s8v*)(dst + 8) = r1;
        }
        return;
    }

    const float scale = (z == 0) ? QSCALE : 1.0f;
    short* out = (z == 0) ? Qo : Ko;

    #pragma unroll
    for (int nt = 0; nt < 4; nt++) {
        const int col = n0 + wn + nt * 16 + ln;
        const float bvv = bias[col];
        #pragma unroll
        for (int mt = 0; mt < 4; mt++) {
            const int row0 = m0 + wm + mt * 16 + hi * 4;
            #pragma unroll
            for (int i = 0; i < 4; i++)
                out[(size_t)(row0 + i) * Csz + col] = (short)bfr((acc[mt][nt][i] + bvv) * scale);
        }
    }
}

// ---------------- output projection GEMM v2 (f32 out), double-buffered staging ----------------
__global__ __launch_bounds__(256, 2) void proj_gemm(
    const short* __restrict__ A, const short* __restrict__ W,
    const float* __restrict__ bias, float* __restrict__ out)
{
    __shared__ __align__(16) short Ash[2][128 * 32];
    __shared__ __align__(16) short Bsh[2][64 * 32];

    const int tid = threadIdx.x, lane = tid & 63, wave = tid >> 6;
    const int ln = lane & 15, hi = lane >> 4;
    const int m0 = blockIdx.x * 128, n0 = blockIdx.y * 64;
    const int wm = (wave >> 1) * 64, wn = (wave & 1) * 32;

    const short* Ag = A + (size_t)(m0 + (tid >> 2)) * Csz + (tid & 3) * 8;
    const short* Bg = W + (size_t)(n0 + (tid >> 2)) * Csz + (tid & 3) * 8;

    f4v acc[4][2];
    #pragma unroll
    for (int mt = 0; mt < 4; mt++)
        #pragma unroll
        for (int nt = 0; nt < 2; nt++)
            #pragma unroll
            for (int i = 0; i < 4; i++) acc[mt][nt][i] = 0.f;

    #define PSTAGE(B, k0_) {                                              \
        gload_lds(Ag + (k0_), Ash[B] + tid * 8);                          \
        gload_lds(Ag + (k0_) + (size_t)64 * Csz, Ash[B] + 2048 + tid * 8);\
        gload_lds(Bg + (k0_), Bsh[B] + tid * 8);                          \
    }

    PSTAGE(0, 0);
    asm volatile("s_waitcnt vmcnt(0)" ::: "memory");
    __builtin_amdgcn_s_barrier();

    #define PTILE(B, k0_) {                                                         \
        const bool more_ = (k0_) + 32 < Csz;                                        \
        if (more_) PSTAGE(B ^ 1, (k0_) + 32);                                       \
        s8v af[4], bf_[2];                                                          \
        for (int mt = 0; mt < 4; mt++)                                              \
            af[mt] = *(const s8v*)(Ash[B] + (wm + mt * 16 + ln) * 32 + hi * 8);     \
        for (int nt = 0; nt < 2; nt++)                                              \
            bf_[nt] = *(const s8v*)(Bsh[B] + (wn + nt * 16 + ln) * 32 + hi * 8);    \
        for (int mt = 0; mt < 4; mt++)                                              \
            for (int nt = 0; nt < 2; nt++)                                          \
                acc[mt][nt] = __builtin_amdgcn_mfma_f32_16x16x32_bf16(af[mt], bf_[nt], acc[mt][nt], 0, 0, 0); \
        if (more_) {                                                                \
            asm volatile("s_waitcnt vmcnt(0)" ::: "memory");                        \
            __builtin_amdgcn_s_barrier();                                           \
        }                                                                           \
    }

    for (int k0 = 0; k0 < Csz; k0 += 64) {
        PTILE(0, k0);
        PTILE(1, k0 + 32);
    }
    #undef PTILE
    #undef PSTAGE

    #pragma unroll
    for (int nt = 0; nt < 2; nt++) {
        const int col = n0 + wn + nt * 16 + ln;
        const float bvv = bias[col];
        #pragma unroll
        for (int mt = 0; mt < 4; mt++)
            #pragma unroll
            for (int i = 0; i < 4; i++)
                out[(size_t)(m0 + wm + mt * 16 + hi * 4 + i) * Csz + col] = acc[mt][nt][i] + bvv;
    }
}

// ---------------- Flash attention v17 (VERBATIM from round 9 — measured 42.1 us, green) ----------------
// v18 lesson: 4 q-tiles @ 256 blocks = 1 block/CU broke stall overlap (54.2 us
// despite FETCH 90->12 MB). v17's 2 blocks/CU is the working point.
__global__ __launch_bounds__(256, 2) void attn17(
    const short* __restrict__ Q, const short* __restrict__ Kg,
    const short* __restrict__ Vt, short* __restrict__ Y)
{
    __shared__ __align__(16) short SB[2][2][64 * 64];   // [buf][K/V][row][swizzled 16B slots]

    const int tid = threadIdx.x, lane = tid & 63, wave = tid >> 6;
    const int ln = lane & 15, hi = lane >> 4;

    const int n = blockIdx.x;
    const int j = n >> 8, n0 = n & 255;
    const int bh = n0 >> 3, ti = n0 & 7;
    const int t = j ? (15 - ti) : ti;                 // 0..15
    const int qts_[2] = { t, 31 - t };                // light, heavy
    const int nkb = 32 - t;                           // key-tiles (heavy's need)

    const size_t base = (size_t)(bh >> 4) * Tsz * Csz + (size_t)(bh & 15) * 64;
    const size_t vtbase = (size_t)bh * 64 * Tsz;
    const int qrel = wave * 16 + ln;                  // within-tile q row (MFMA n-col)

    s8v qf[2][2];
    #pragma unroll
    for (int tt = 0; tt < 2; tt++)
        #pragma unroll
        for (int kk = 0; kk < 2; kk++)
            qf[tt][kk] = *(const s8v*)(Q + base + (size_t)(qts_[tt] * 64 + qrel) * Csz + kk * 32 + hi * 8);

    f4v o[2][4];
    f4v lacc[2];
    #pragma unroll
    for (int tt = 0; tt < 2; tt++) {
        #pragma unroll
        for (int i = 0; i < 4; i++) lacc[tt][i] = 0.f;
        #pragma unroll
        for (int dt = 0; dt < 4; dt++)
            #pragma unroll
            for (int i = 0; i < 4; i++) o[tt][dt][i] = 0.f;
    }

    const s8v ones8 = { (short)0x3F80, (short)0x3F80, (short)0x3F80, (short)0x3F80,
                        (short)0x3F80, (short)0x3F80, (short)0x3F80, (short)0x3F80 };

    const int sr = tid >> 3, scs = tid & 7;
    const int csw = (scs ^ (sr & 7)) * 8;             // pre-swizzled col offset (shorts)
    const short* KsA = Kg + base + (size_t)sr * Csz + csw;
    const short* KsB = KsA + (size_t)32 * Csz;
    const short* VsA = Vt + vtbase + (size_t)sr * Tsz + csw;
    const short* VsB = VsA + (size_t)32 * Tsz;

    int foff[2][4];
    #pragma unroll
    for (int nt = 0; nt < 4; nt++)
        #pragma unroll
        for (int kk = 0; kk < 2; kk++)
            foff[kk][nt] = (nt * 16 + ln) * 64 + (((kk * 4 + hi) ^ (ln & 7)) * 8);

    #define STAGE(B, kb_) {                                      \
        const size_t ko_ = (size_t)(kb_) * 64;                   \
        gload_lds(KsA + ko_ * Csz, &SB[B][0][tid * 8]);          \
        gload_lds(KsB + ko_ * Csz, &SB[B][0][2048 + tid * 8]);   \
        gload_lds(VsA + ko_,       &SB[B][1][tid * 8]);          \
        gload_lds(VsB + ko_,       &SB[B][1][2048 + tid * 8]);   \
    }

    STAGE(0, 0);
    asm volatile("s_waitcnt vmcnt(0)" ::: "memory");
    __builtin_amdgcn_s_barrier();

    #define TILE(B0, B1, kb_) {                                                     \
        const bool st_ = (kb_) + 1 < nkb;                                           \
        if (st_) STAGE(B1, (kb_) + 1);                                              \
        s8v kf[2][4], vf[2][4];                                                     \
        for (int nt = 0; nt < 4; nt++) {                                            \
            kf[0][nt] = *(const s8v*)(&SB[B0][0][foff[0][nt]]);                     \
            kf[1][nt] = *(const s8v*)(&SB[B0][0][foff[1][nt]]);                     \
            vf[0][nt] = *(const s8v*)(&SB[B0][1][foff[0][nt]]);                     \
            vf[1][nt] = *(const s8v*)(&SB[B0][1][foff[1][nt]]);                     \
        }                                                                           \
        _Pragma("unroll")                                                           \
        for (int tt = 0; tt < 2; tt++) {                                            \
            if ((kb_) > qts_[tt]) continue;          /* wave-uniform */             \
            f4v s[4];                                                               \
            for (int nt = 0; nt < 4; nt++) {                                        \
                for (int i = 0; i < 4; i++) s[nt][i] = 0.f;                         \
                s[nt] = __builtin_amdgcn_mfma_f32_16x16x32_bf16(kf[0][nt], qf[tt][0], s[nt], 0, 0, 0); \
                s[nt] = __builtin_amdgcn_mfma_f32_16x16x32_bf16(kf[1][nt], qf[tt][1], s[nt], 0, 0, 0); \
            }                                                                       \
            const bool dg_ = ((kb_) == qts_[tt]);                                   \
            unsigned pw[4][2];                                                      \
            for (int nt = 0; nt < 4; nt++) {                                        \
                float e0 = exp2f(s[nt][0]), e1 = exp2f(s[nt][1]);                   \
                float e2 = exp2f(s[nt][2]), e3 = exp2f(s[nt][3]);                   \
                if (dg_) {                                                          \
                    const int kr = nt * 16 + hi * 4;                                \
                    if (kr + 0 > qrel) e0 = 0.f;                                    \
                    if (kr + 1 > qrel) e1 = 0.f;                                    \
                    if (kr + 2 > qrel) e2 = 0.f;                                    \
                    if (kr + 3 > qrel) e3 = 0.f;                                    \
                }                                                                   \
                pw[nt][0] = cvt2(e0, e1);                                           \
                pw[nt][1] = cvt2(e2, e3);                                           \
            }                                                                       \
            u2v r0a = __builtin_amdgcn_permlane32_swap(pw[0][0], pw[1][0], false, false); \
            u2v r0b = __builtin_amdgcn_permlane16_swap(r0a[0], r0a[1], false, false); \
            u2v r1a = __builtin_amdgcn_permlane32_swap(pw[0][1], pw[1][1], false, false); \
            u2v r1b = __builtin_amdgcn_permlane16_swap(r1a[0], r1a[1], false, false); \
            u2v r2a = __builtin_amdgcn_permlane32_swap(pw[2][0], pw[3][0], false, false); \
            u2v r2b = __builtin_amdgcn_permlane16_swap(r2a[0], r2a[1], false, false); \
            u2v r3a = __builtin_amdgcn_permlane32_swap(pw[2][1], pw[3][1], false, false); \
            u2v r3b = __builtin_amdgcn_permlane16_swap(r3a[0], r3a[1], false, false); \
            i4v p0 = { (int)r0b[0], (int)r1b[0], (int)r0b[1], (int)r1b[1] };        \
            i4v p1 = { (int)r2b[0], (int)r3b[0], (int)r2b[1], (int)r3b[1] };        \
            const s8v pb0 = __builtin_bit_cast(s8v, p0);                            \
            const s8v pb1 = __builtin_bit_cast(s8v, p1);                            \
            for (int dt = 0; dt < 4; dt++) {                                        \
                o[tt][dt] = __builtin_amdgcn_mfma_f32_16x16x32_bf16(vf[0][dt], pb0, o[tt][dt], 0, 0, 0); \
                o[tt][dt] = __builtin_amdgcn_mfma_f32_16x16x32_bf16(vf[1][dt], pb1, o[tt][dt], 0, 0, 0); \
            }                                                                       \
            lacc[tt] = __builtin_amdgcn_mfma_f32_16x16x32_bf16(ones8, pb0, lacc[tt], 0, 0, 0); \
            lacc[tt] = __builtin_amdgcn_mfma_f32_16x16x32_bf16(ones8, pb1, lacc[tt], 0, 0, 0); \
        }                                                                           \
        if (st_) {                                                                  \
            asm volatile("s_waitcnt vmcnt(0)" ::: "memory");                        \
            __builtin_amdgcn_s_barrier();                                           \
        }                                                                           \
    }

    for (int kb = 0; kb < nkb; kb += 2) {
        TILE(0, 1, kb);
        if (kb + 1 < nkb) TILE(1, 0, kb + 1);
    }
    #undef TILE
    #undef STAGE

    #pragma unroll
    for (int tt = 0; tt < 2; tt++) {
        const float inv = 1.0f / lacc[tt][0];
        const int qrow = qts_[tt] * 64 + qrel;
        #pragma unroll
        for (int dt = 0; dt < 4; dt++) {
            int2 w;
            w.x = (int)cvt2(o[tt][dt][0] * inv, o[tt][dt][1] * inv);
            w.y = (int)cvt2(o[tt][dt][2] * inv, o[tt][dt][3] * inv);
            *(int2*)(Y + base + (size_t)qrow * Csz + dt * 16 + hi * 4) = w;
        }
    }
}

extern "C" void kernel_launch(void* const* d_in, const int* in_sizes, int n_in,
                              void* d_out, int out_size, void* d_ws, size_t ws_size,
                              hipStream_t stream) {
    const float* x  = (const float*)d_in[0];
    const float* Wq = (const float*)d_in[1];
    const float* bq = (const float*)d_in[2];
    const float* Wk = (const float*)d_in[3];
    const float* bk = (const float*)d_in[4];
    const float* Wv = (const float*)d_in[5];
    const float* bv = (const float*)d_in[6];
    const float* Wp = (const float*)d_in[7];
    const float* bp = (const float*)d_in[8];

    char* ws = (char*)d_ws;
    short* Xb  = (short*)(ws);                 // 8 MB
    short* Wqb = (short*)(ws + (8u  << 20));   // 2 MB each
    short* Wkb = (short*)(ws + (10u << 20));
    short* Wvb = (short*)(ws + (12u << 20));
    short* Wpb = (short*)(ws + (14u << 20));
    short* Qb  = (short*)(ws + (16u << 20));   // 8 MB each
    short* Kb  = (short*)(ws + (24u << 20));
    short* Vtb = (short*)(ws + (32u << 20));   // V transposed per head [B*H*64, T]
    short* Yb  = (short*)(ws + (40u << 20));

    hipLaunchKernelGGL(cvt6, dim3(8192), dim3(256), 0, stream,
                       x, Wq, Wk, Wv, Wp, Xb, Wqb, Wkb, Wvb, Wpb);

    hipLaunchKernelGGL(qkv_gemm, dim3(32, 8, 3), dim3(256), 0, stream,
                       Xb, Wqb, Wkb, Wvb, bq, bk, bv, Qb, Kb, Vtb);

    hipLaunchKernelGGL(attn17, dim3(512), dim3(256), 0, stream, Qb, Kb, Vtb, Yb);

    hipLaunchKernelGGL(proj_gemm, dim3(32, 16), dim3(256), 0, stream, Yb, Wpb, bp, (float*)d_out);
}

// Round 12
// 184.434 us; speedup vs baseline: 1.0469x; 1.0060x over previous
//
#include <hip/hip_runtime.h>
#include <hip/hip_bf16.h>

#define Tsz 2048
#define Csz 1024
#define Hn 16

typedef short s8v __attribute__((ext_vector_type(8)));
typedef short s4v __attribute__((ext_vector_type(4)));
typedef float f4v __attribute__((ext_vector_type(4)));
typedef int   i4v __attribute__((ext_vector_type(4)));
typedef unsigned u2v __attribute__((ext_vector_type(2)));

#define QSCALE (0.125f * 1.44269504088896f)  // 1/sqrt(64) * log2(e), folded into Q

// fast bf16 round (bits+0x8000)>>16 : 2 VALU vs ~6 for software RNE
__device__ __forceinline__ unsigned short bfr(float x) {
    return (unsigned short)((__builtin_bit_cast(unsigned, x) + 0x8000u) >> 16);
}
__device__ __forceinline__ unsigned pack2_rn(float a, float b) {
    const unsigned ua = __builtin_bit_cast(unsigned, a) + 0x8000u;
    const unsigned ub = __builtin_bit_cast(unsigned, b) + 0x8000u;
    return (ua >> 16) | (ub & 0xFFFF0000u);
}
// v_cvt_pk_bf16_f32 via HIP conversion (compiler emits the packed cvt; a->low, b->high)
// NOTE: __hip_bfloat162 is not trivially copyable in this ROCm -> memcpy, not bit_cast.
__device__ __forceinline__ unsigned cvt2(float a, float b) {
    __hip_bfloat162 h = __float22bfloat162_rn(float2{a, b});
    unsigned r;
    __builtin_memcpy(&r, &h, 4);
    return r;
}

__device__ __forceinline__ void gload_lds(const void* g, void* l) {
    __builtin_amdgcn_global_load_lds(
        (const __attribute__((address_space(1))) void*)g,
        (__attribute__((address_space(3))) void*)l, 16, 0, 0);
}

// ---------------- fp32 -> bf16 conversion, exact-size grid (8192 blocks) ----------------
__global__ void cvt6(const float* __restrict__ x, const float* __restrict__ wq,
                     const float* __restrict__ wk, const float* __restrict__ wv,
                     const float* __restrict__ wp,
                     short* __restrict__ xo, short* __restrict__ qo,
                     short* __restrict__ ko, short* __restrict__ vo,
                     short* __restrict__ po) {
    const int bx = blockIdx.x;
    const float* in; short* out; int ib;
    if (bx < 4096) { in = x; out = xo; ib = bx; }
    else {
        const int r = bx - 4096, w = r >> 10;
        ib = r & 1023;
        switch (w) {
            case 0: in = wq; out = qo; break;
            case 1: in = wk; out = ko; break;
            case 2: in = wv; out = vo; break;
            default: in = wp; out = po; break;
        }
    }
    const int i = ib * 1024 + threadIdx.x * 4;
    float4 v = *(const float4*)(in + i);
    int2 o;
    o.x = (int)pack2_rn(v.x, v.y);
    o.y = (int)pack2_rn(v.z, v.w);
    *(int2*)(out + i) = o;
}

// ---------------- fused QKV GEMM (m97 structure; round-9 version — dbuf regressed) ----------------
__global__ __launch_bounds__(256, 3) void qkv_gemm(
    const short* __restrict__ X,
    const short* __restrict__ Wq, const short* __restrict__ Wk, const short* __restrict__ Wv,
    const float* __restrict__ bq, const float* __restrict__ bk, const float* __restrict__ bv,
    short* __restrict__ Qo, short* __restrict__ Ko, short* __restrict__ Vto)
{
    const int z = blockIdx.z;
    const short* W = (z == 0) ? Wq : (z == 1) ? Wk : Wv;
    const float* bias = (z == 0) ? bq : (z == 1) ? bk : bv;

    __shared__ __align__(16) short Ash[128 * 32];
    __shared__ __align__(16) short Bsh[128 * 32];
    __shared__ __align__(16) short TR[64 * 72];   // transpose staging (z==2 epilogue)

    const int tid = threadIdx.x, lane = tid & 63, wave = tid >> 6;
    const int ln = lane & 15, hi = lane >> 4;
    const int m0 = blockIdx.x * 128, n0 = blockIdx.y * 128;
    const int wm = (wave >> 1) * 64, wn = (wave & 1) * 64;

    const short* Ag = X + (size_t)(m0 + (tid >> 2)) * Csz + (tid & 3) * 8;
    const short* Bg = W + (size_t)(n0 + (tid >> 2)) * Csz + (tid & 3) * 8;

    f4v acc[4][4];
    #pragma unroll
    for (int mt = 0; mt < 4; mt++)
        #pragma unroll
        for (int nt = 0; nt < 4; nt++)
            #pragma unroll
            for (int i = 0; i < 4; i++) acc[mt][nt][i] = 0.f;

    for (int k0 = 0; k0 < Csz; k0 += 32) {
        __syncthreads();
        gload_lds(Ag + k0, Ash + tid * 8);
        gload_lds(Ag + k0 + (size_t)64 * Csz, Ash + 2048 + tid * 8);
        gload_lds(Bg + k0, Bsh + tid * 8);
        gload_lds(Bg + k0 + (size_t)64 * Csz, Bsh + 2048 + tid * 8);
        __syncthreads();

        s8v af[4], bfr_[4];
        #pragma unroll
        for (int mt = 0; mt < 4; mt++)
            af[mt] = *(const s8v*)(Ash + (wm + mt * 16 + ln) * 32 + hi * 8);
        #pragma unroll
        for (int nt = 0; nt < 4; nt++)
            bfr_[nt] = *(const s8v*)(Bsh + (wn + nt * 16 + ln) * 32 + hi * 8);
        #pragma unroll
        for (int mt = 0; mt < 4; mt++)
            #pragma unroll
            for (int nt = 0; nt < 4; nt++)
                acc[mt][nt] = __builtin_amdgcn_mfma_f32_16x16x32_bf16(af[mt], bfr_[nt], acc[mt][nt], 0, 0, 0);
    }

    if (z == 2) {
        const int b = m0 >> 11, t0 = m0 & 2047;
        float bvv[4];
        #pragma unroll
        for (int nt = 0; nt < 4; nt++) bvv[nt] = bias[n0 + wn + nt * 16 + ln];
        #pragma unroll
        for (int ph = 0; ph < 4; ph++) {
            const int mh = ph >> 1, nh = ph & 1;
            __syncthreads();
            if ((wave >> 1) == mh && (wave & 1) == nh) {
                #pragma unroll
                for (int mt = 0; mt < 4; mt++)
                    #pragma unroll
                    for (int nt = 0; nt < 4; nt++) {
                        int2 pk;
                        pk.x = (int)pack2_rn(acc[mt][nt][0] + bvv[nt], acc[mt][nt][1] + bvv[nt]);
                        pk.y = (int)pack2_rn(acc[mt][nt][2] + bvv[nt], acc[mt][nt][3] + bvv[nt]);
                        *(int2*)(TR + (nt * 16 + ln) * 72 + mt * 16 + hi * 4) = pk;
                    }
            }
            __syncthreads();
            const int chl = tid >> 2, seg = tid & 3;
            const s8v r0 = *(const s8v*)(TR + chl * 72 + seg * 16);
            const s8v r1 = *(const s8v*)(TR + chl * 72 + seg * 16 + 8);
            short* dst = Vto + (size_t)(b * 1024 + n0 + nh * 64 + chl) * Tsz + t0 + mh * 64 + seg * 16;
            *(s8v*)(dst) = r0;
            *(s8v*)(dst + 8) = r1;
        }
        return;
    }

    const float scale = (z == 0) ? QSCALE : 1.0f;
    short* out = (z == 0) ? Qo : Ko;

    #pragma unroll
    for (int nt = 0; nt < 4; nt++) {
        const int col = n0 + wn + nt * 16 + ln;
        const float bvv = bias[col];
        #pragma unroll
        for (int mt = 0; mt < 4; mt++) {
            const int row0 = m0 + wm + mt * 16 + hi * 4;
            #pragma unroll
            for (int i = 0; i < 4; i++)
                out[(size_t)(row0 + i) * Csz + col] = (short)bfr((acc[mt][nt][i] + bvv) * scale);
        }
    }
}

// ---------------- output projection GEMM (f32 out; round-9 version) ----------------
__global__ __launch_bounds__(256, 2) void proj_gemm(
    const short* __restrict__ A, const short* __restrict__ W,
    const float* __restrict__ bias, float* __restrict__ out)
{
    __shared__ __align__(16) short Ash[128 * 32];
    __shared__ __align__(16) short Bsh[64 * 32];

    const int tid = threadIdx.x, lane = tid & 63, wave = tid >> 6;
    const int ln = lane & 15, hi = lane >> 4;
    const int m0 = blockIdx.x * 128, n0 = blockIdx.y * 64;
    const int wm = (wave >> 1) * 64, wn = (wave & 1) * 32;

    const short* Ag = A + (size_t)(m0 + (tid >> 2)) * Csz + (tid & 3) * 8;
    const short* Bg = W + (size_t)(n0 + (tid >> 2)) * Csz + (tid & 3) * 8;

    f4v acc[4][2];
    #pragma unroll
    for (int mt = 0; mt < 4; mt++)
        #pragma unroll
        for (int nt = 0; nt < 2; nt++)
            #pragma unroll
            for (int i = 0; i < 4; i++) acc[mt][nt][i] = 0.f;

    for (int k0 = 0; k0 < Csz; k0 += 32) {
        __syncthreads();
        gload_lds(Ag + k0, Ash + tid * 8);
        gload_lds(Ag + k0 + (size_t)64 * Csz, Ash + 2048 + tid * 8);
        gload_lds(Bg + k0, Bsh + tid * 8);
        __syncthreads();

        s8v af[4], bfr_[2];
        #pragma unroll
        for (int mt = 0; mt < 4; mt++)
            af[mt] = *(const s8v*)(Ash + (wm + mt * 16 + ln) * 32 + hi * 8);
        #pragma unroll
        for (int nt = 0; nt < 2; nt++)
            bfr_[nt] = *(const s8v*)(Bsh + (wn + nt * 16 + ln) * 32 + hi * 8);
        #pragma unroll
        for (int mt = 0; mt < 4; mt++)
            #pragma unroll
            for (int nt = 0; nt < 2; nt++)
                acc[mt][nt] = __builtin_amdgcn_mfma_f32_16x16x32_bf16(af[mt], bfr_[nt], acc[mt][nt], 0, 0, 0);
    }

    #pragma unroll
    for (int nt = 0; nt < 2; nt++) {
        const int col = n0 + wn + nt * 16 + ln;
        const float bvv = bias[col];
        #pragma unroll
        for (int mt = 0; mt < 4; mt++)
            #pragma unroll
            for (int i = 0; i < 4; i++)
                out[(size_t)(m0 + wm + mt * 16 + hi * 4 + i) * Csz + col] = acc[mt][nt][i] + bvv;
    }
}

// ---------------- Flash attention v19: v17 core, KVBLK 64->128 ----------------
// Model (v16/v17): t = 18.5us + ~1.9ns * staging-iterations; v18: must keep
// >=2 blocks/CU. KVBLK=128 halves iterations (12544 -> 6400) at 64KB LDS ->
// still 2 blocks/CU. Per-block compute perfectly uniform: 17 128-key tiles
// for every t; co-resident pair (n, n+256) stages 25 tiles total.
// Causal on 128-key tiles: skip kb > qt>>1; diagonal kb == qt>>1 with mask
// threshold qrel + 64*(qt&1). K LDS [128][64], V LDS [64][128]; same green
// XOR swizzle (slot ^= row&7; pass strides 32/16 are 0 mod 8).
__global__ __launch_bounds__(256, 2) void attn19(
    const short* __restrict__ Q, const short* __restrict__ Kg,
    const short* __restrict__ Vt, short* __restrict__ Y)
{
    __shared__ __align__(16) short SB[2][2][128 * 64];  // [buf][0:K[128][64] | 1:V[64][128]]

    const int tid = threadIdx.x, lane = tid & 63, wave = tid >> 6;
    const int ln = lane & 15, hi = lane >> 4;

    const int n = blockIdx.x;
    const int j = n >> 8, n0 = n & 255;
    const int bh = n0 >> 3, ti = n0 & 7;
    const int t = j ? (15 - ti) : ti;                 // 0..15
    const int qts_[2] = { t, 31 - t };                // light, heavy
    const int dgk_[2] = { t >> 1, (31 - t) >> 1 };    // diagonal 128-tile index
    const int nkb = dgk_[1] + 1;                      // 9..16

    const size_t base = (size_t)(bh >> 4) * Tsz * Csz + (size_t)(bh & 15) * 64;
    const size_t vtbase = (size_t)bh * 64 * Tsz;
    const int qrel = wave * 16 + ln;                  // within-tile q row (MFMA n-col)
    const int thr_[2] = { qrel + ((t & 1) << 6), qrel + (((31 - t) & 1) << 6) };

    s8v qf[2][2];
    #pragma unroll
    for (int tt = 0; tt < 2; tt++)
        #pragma unroll
        for (int kk = 0; kk < 2; kk++)
            qf[tt][kk] = *(const s8v*)(Q + base + (size_t)(qts_[tt] * 64 + qrel) * Csz + kk * 32 + hi * 8);

    f4v o[2][4];
    f4v lacc[2];
    #pragma unroll
    for (int tt = 0; tt < 2; tt++) {
        #pragma unroll
        for (int i = 0; i < 4; i++) lacc[tt][i] = 0.f;
        #pragma unroll
        for (int dt = 0; dt < 4; dt++)
            #pragma unroll
            for (int i = 0; i < 4; i++) o[tt][dt][i] = 0.f;
    }

    const s8v ones8 = { (short)0x3F80, (short)0x3F80, (short)0x3F80, (short)0x3F80,
                        (short)0x3F80, (short)0x3F80, (short)0x3F80, (short)0x3F80 };

    // K staging: thread -> row sr (+32p), slot scs; pre-swizzled global col.
    const int sr = tid >> 3, scs = tid & 7;
    const short* KsA = Kg + base + (size_t)sr * Csz + (scs ^ (sr & 7)) * 8;
    // V staging: thread -> row vr (+16p), slot vscs (16 slots/row of 128 keys).
    const int vr = tid >> 4, vscs = tid & 15;
    const short* VsA = Vt + vtbase + (size_t)vr * Tsz + (vscs ^ (vr & 7)) * 8;

    // fragment-read offsets (swizzle by ln&7): K rows nt*16+ln (nt 0..7, pitch 64);
    // V rows dt*16+ln (pitch 128), key-chunk kk 0..3.
    int fk[2][8];
    #pragma unroll
    for (int nt = 0; nt < 8; nt++)
        #pragma unroll
        for (int kk = 0; kk < 2; kk++)
            fk[kk][nt] = (nt * 16 + ln) * 64 + (((kk * 4 + hi) ^ (ln & 7)) * 8);
    int fv[4][4];
    #pragma unroll
    for (int dt = 0; dt < 4; dt++)
        #pragma unroll
        for (int kk = 0; kk < 4; kk++)
            fv[kk][dt] = (dt * 16 + ln) * 128 + (((kk * 4 + hi) ^ (ln & 7)) * 8);

    #define STAGE(B, kb_) {                                              \
        const short* kp_ = KsA + (size_t)(kb_) * 128 * Csz;              \
        const short* vp_ = VsA + (size_t)(kb_) * 128;                    \
        gload_lds(kp_,                   &SB[B][0][tid * 8]);            \
        gload_lds(kp_ + (size_t)32*Csz,  &SB[B][0][2048 + tid * 8]);     \
        gload_lds(kp_ + (size_t)64*Csz,  &SB[B][0][4096 + tid * 8]);     \
        gload_lds(kp_ + (size_t)96*Csz,  &SB[B][0][6144 + tid * 8]);     \
        gload_lds(vp_,                   &SB[B][1][tid * 8]);            \
        gload_lds(vp_ + (size_t)16*Tsz,  &SB[B][1][2048 + tid * 8]);     \
        gload_lds(vp_ + (size_t)32*Tsz,  &SB[B][1][4096 + tid * 8]);     \
        gload_lds(vp_ + (size_t)48*Tsz,  &SB[B][1][6144 + tid * 8]);     \
    }

    STAGE(0, 0);
    asm volatile("s_waitcnt vmcnt(0)" ::: "memory");
    __builtin_amdgcn_s_barrier();

    #define TILE(B0, B1, kb_) {                                                     \
        const bool st_ = (kb_) + 1 < nkb;                                           \
        if (st_) STAGE(B1, (kb_) + 1);                                              \
        s8v pbt[2][4];                                                              \
        bool act[2];                                                                \
        act[0] = (kb_) <= dgk_[0];                                                  \
        act[1] = (kb_) <= dgk_[1];                                                  \
        _Pragma("unroll")                                                           \
        for (int tt = 0; tt < 2; tt++) {                                            \
            if (!act[tt]) continue;              /* wave-uniform */                 \
            f4v s[8];                                                               \
            for (int nt = 0; nt < 8; nt++) {                                        \
                const s8v k0_ = *(const s8v*)(&SB[B0][0][fk[0][nt]]);               \
                const s8v k1_ = *(const s8v*)(&SB[B0][0][fk[1][nt]]);               \
                for (int i = 0; i < 4; i++) s[nt][i] = 0.f;                         \
                s[nt] = __builtin_amdgcn_mfma_f32_16x16x32_bf16(k0_, qf[tt][0], s[nt], 0, 0, 0); \
                s[nt] = __builtin_amdgcn_mfma_f32_16x16x32_bf16(k1_, qf[tt][1], s[nt], 0, 0, 0); \
            }                                                                       \
            const bool dg_ = ((kb_) == dgk_[tt]);                                   \
            const int thr = thr_[tt];                                               \
            unsigned pw[8][2];                                                      \
            for (int nt = 0; nt < 8; nt++) {                                        \
                float e0 = exp2f(s[nt][0]), e1 = exp2f(s[nt][1]);                   \
                float e2 = exp2f(s[nt][2]), e3 = exp2f(s[nt][3]);                   \
                if (dg_) {                                                          \
                    const int kr = nt * 16 + hi * 4;                                \
                    if (kr + 0 > thr) e0 = 0.f;                                     \
                    if (kr + 1 > thr) e1 = 0.f;                                     \
                    if (kr + 2 > thr) e2 = 0.f;                                     \
                    if (kr + 3 > thr) e3 = 0.f;                                     \
                }                                                                   \
                pw[nt][0] = cvt2(e0, e1);                                           \
                pw[nt][1] = cvt2(e2, e3);                                           \
            }                                                                       \
            for (int e = 0; e < 4; e++) {                                           \
                u2v ra = __builtin_amdgcn_permlane32_swap(pw[2*e][0], pw[2*e+1][0], false, false); \
                u2v rb = __builtin_amdgcn_permlane16_swap(ra[0], ra[1], false, false); \
                u2v rc = __builtin_amdgcn_permlane32_swap(pw[2*e][1], pw[2*e+1][1], false, false); \
                u2v rd = __builtin_amdgcn_permlane16_swap(rc[0], rc[1], false, false); \
                i4v pp = { (int)rb[0], (int)rd[0], (int)rb[1], (int)rd[1] };        \
                pbt[tt][e] = __builtin_bit_cast(s8v, pp);                           \
            }                                                                       \
        }                                                                           \
        _Pragma("unroll")                                                           \
        for (int kk = 0; kk < 4; kk++) {                                            \
            s8v vfr[4];                                                             \
            for (int dt = 0; dt < 4; dt++)                                          \
                vfr[dt] = *(const s8v*)(&SB[B0][1][fv[kk][dt]]);                    \
            for (int tt = 0; tt < 2; tt++) {                                        \
                if (!act[tt]) continue;                                             \
                for (int dt = 0; dt < 4; dt++)                                      \
                    o[tt][dt] = __builtin_amdgcn_mfma_f32_16x16x32_bf16(vfr[dt], pbt[tt][kk], o[tt][dt], 0, 0, 0); \
                lacc[tt] = __builtin_amdgcn_mfma_f32_16x16x32_bf16(ones8, pbt[tt][kk], lacc[tt], 0, 0, 0); \
            }                                                                       \
        }                                                                           \
        if (st_) {                                                                  \
            asm volatile("s_waitcnt vmcnt(0)" ::: "memory");                        \
            __builtin_amdgcn_s_barrier();                                           \
        }                                                                           \
    }

    for (int kb = 0; kb < nkb; kb += 2) {
        TILE(0, 1, kb);
        if (kb + 1 < nkb) TILE(1, 0, kb + 1);
    }
    #undef TILE
    #undef STAGE

    // l for q=ln fully reduced in lacc[tt] (ones-MFMA over all keys)
    #pragma unroll
    for (int tt = 0; tt < 2; tt++) {
        const float inv = 1.0f / lacc[tt][0];
        const int qrow = qts_[tt] * 64 + qrel;
        #pragma unroll
        for (int dt = 0; dt < 4; dt++) {
            int2 w;
            w.x = (int)cvt2(o[tt][dt][0] * inv, o[tt][dt][1] * inv);
            w.y = (int)cvt2(o[tt][dt][2] * inv, o[tt][dt][3] * inv);
            *(int2*)(Y + base + (size_t)qrow * Csz + dt * 16 + hi * 4) = w;
        }
    }
}

extern "C" void kernel_launch(void* const* d_in, const int* in_sizes, int n_in,
                              void* d_out, int out_size, void* d_ws, size_t ws_size,
                              hipStream_t stream) {
    const float* x  = (const float*)d_in[0];
    const float* Wq = (const float*)d_in[1];
    const float* bq = (const float*)d_in[2];
    const float* Wk = (const float*)d_in[3];
    const float* bk = (const float*)d_in[4];
    const float* Wv = (const float*)d_in[5];
    const float* bv = (const float*)d_in[6];
    const float* Wp = (const float*)d_in[7];
    const float* bp = (const float*)d_in[8];

    char* ws = (char*)d_ws;
    short* Xb  = (short*)(ws);                 // 8 MB
    short* Wqb = (short*)(ws + (8u  << 20));   // 2 MB each
    short* Wkb = (short*)(ws + (10u << 20));
    short* Wvb = (short*)(ws + (12u << 20));
    short* Wpb = (short*)(ws + (14u << 20));
    short* Qb  = (short*)(ws + (16u << 20));   // 8 MB each
    short* Kb  = (short*)(ws + (24u << 20));
    short* Vtb = (short*)(ws + (32u << 20));   // V transposed per head [B*H*64, T]
    short* Yb  = (short*)(ws + (40u << 20));

    hipLaunchKernelGGL(cvt6, dim3(8192), dim3(256), 0, stream,
                       x, Wq, Wk, Wv, Wp, Xb, Wqb, Wkb, Wvb, Wpb);

    hipLaunchKernelGGL(qkv_gemm, dim3(32, 8, 3), dim3(256), 0, stream,
                       Xb, Wqb, Wkb, Wvb, bq, bk, bv, Qb, Kb, Vtb);

    hipLaunchKernelGGL(attn19, dim3(512), dim3(256), 0, stream, Qb, Kb, Vtb, Yb);

    hipLaunchKernelGGL(proj_gemm, dim3(32, 16), dim3(256), 0, stream, Yb, Wpb, bp, (float*)d_out);
}

// Round 14
// 180.857 us; speedup vs baseline: 1.0676x; 1.0198x over previous
//
#include <hip/hip_runtime.h>
#include <hip/hip_bf16.h>

#define Tsz 2048
#define Csz 1024
#define Hn 16

typedef short s8v __attribute__((ext_vector_type(8)));
typedef short s4v __attribute__((ext_vector_type(4)));
typedef float f4v __attribute__((ext_vector_type(4)));
typedef int   i4v __attribute__((ext_vector_type(4)));
typedef unsigned u2v __attribute__((ext_vector_type(2)));

#define QSCALE (0.125f * 1.44269504088896f)  // 1/sqrt(64) * log2(e), folded into Q

// fast bf16 round (bits+0x8000)>>16 : 2 VALU vs ~6 for software RNE
__device__ __forceinline__ unsigned short bfr(float x) {
    return (unsigned short)((__builtin_bit_cast(unsigned, x) + 0x8000u) >> 16);
}
__device__ __forceinline__ unsigned pack2_rn(float a, float b) {
    const unsigned ua = __builtin_bit_cast(unsigned, a) + 0x8000u;
    const unsigned ub = __builtin_bit_cast(unsigned, b) + 0x8000u;
    return (ua >> 16) | (ub & 0xFFFF0000u);
}
// v_cvt_pk_bf16_f32 via HIP conversion (compiler emits the packed cvt; a->low, b->high)
// NOTE: __hip_bfloat162 is not trivially copyable in this ROCm -> memcpy, not bit_cast.
__device__ __forceinline__ unsigned cvt2(float a, float b) {
    __hip_bfloat162 h = __float22bfloat162_rn(float2{a, b});
    unsigned r;
    __builtin_memcpy(&r, &h, 4);
    return r;
}

__device__ __forceinline__ void gload_lds(const void* g, void* l) {
    __builtin_amdgcn_global_load_lds(
        (const __attribute__((address_space(1))) void*)g,
        (__attribute__((address_space(3))) void*)l, 16, 0, 0);
}

// ---------------- fp32 -> bf16 conversion, exact-size grid (8192 blocks) ----------------
__global__ void cvt6(const float* __restrict__ x, const float* __restrict__ wq,
                     const float* __restrict__ wk, const float* __restrict__ wv,
                     const float* __restrict__ wp,
                     short* __restrict__ xo, short* __restrict__ qo,
                     short* __restrict__ ko, short* __restrict__ vo,
                     short* __restrict__ po) {
    const int bx = blockIdx.x;
    const float* in; short* out; int ib;
    if (bx < 4096) { in = x; out = xo; ib = bx; }
    else {
        const int r = bx - 4096, w = r >> 10;
        ib = r & 1023;
        switch (w) {
            case 0: in = wq; out = qo; break;
            case 1: in = wk; out = ko; break;
            case 2: in = wv; out = vo; break;
            default: in = wp; out = po; break;
        }
    }
    const int i = ib * 1024 + threadIdx.x * 4;
    float4 v = *(const float4*)(in + i);
    int2 o;
    o.x = (int)pack2_rn(v.x, v.y);
    o.y = (int)pack2_rn(v.z, v.w);
    *(int2*)(out + i) = o;
}

// ---------------- fused QKV GEMM (m97 structure; round-9 version) ----------------
__global__ __launch_bounds__(256, 3) void qkv_gemm(
    const short* __restrict__ X,
    const short* __restrict__ Wq, const short* __restrict__ Wk, const short* __restrict__ Wv,
    const float* __restrict__ bq, const float* __restrict__ bk, const float* __restrict__ bv,
    short* __restrict__ Qo, short* __restrict__ Ko, short* __restrict__ Vto)
{
    const int z = blockIdx.z;
    const short* W = (z == 0) ? Wq : (z == 1) ? Wk : Wv;
    const float* bias = (z == 0) ? bq : (z == 1) ? bk : bv;

    __shared__ __align__(16) short Ash[128 * 32];
    __shared__ __align__(16) short Bsh[128 * 32];
    __shared__ __align__(16) short TR[64 * 72];   // transpose staging (z==2 epilogue)

    const int tid = threadIdx.x, lane = tid & 63, wave = tid >> 6;
    const int ln = lane & 15, hi = lane >> 4;
    const int m0 = blockIdx.x * 128, n0 = blockIdx.y * 128;
    const int wm = (wave >> 1) * 64, wn = (wave & 1) * 64;

    const short* Ag = X + (size_t)(m0 + (tid >> 2)) * Csz + (tid & 3) * 8;
    const short* Bg = W + (size_t)(n0 + (tid >> 2)) * Csz + (tid & 3) * 8;

    f4v acc[4][4];
    #pragma unroll
    for (int mt = 0; mt < 4; mt++)
        #pragma unroll
        for (int nt = 0; nt < 4; nt++)
            #pragma unroll
            for (int i = 0; i < 4; i++) acc[mt][nt][i] = 0.f;

    for (int k0 = 0; k0 < Csz; k0 += 32) {
        __syncthreads();
        gload_lds(Ag + k0, Ash + tid * 8);
        gload_lds(Ag + k0 + (size_t)64 * Csz, Ash + 2048 + tid * 8);
        gload_lds(Bg + k0, Bsh + tid * 8);
        gload_lds(Bg + k0 + (size_t)64 * Csz, Bsh + 2048 + tid * 8);
        __syncthreads();

        s8v af[4], bfr_[4];
        #pragma unroll
        for (int mt = 0; mt < 4; mt++)
            af[mt] = *(const s8v*)(Ash + (wm + mt * 16 + ln) * 32 + hi * 8);
        #pragma unroll
        for (int nt = 0; nt < 4; nt++)
            bfr_[nt] = *(const s8v*)(Bsh + (wn + nt * 16 + ln) * 32 + hi * 8);
        #pragma unroll
        for (int mt = 0; mt < 4; mt++)
            #pragma unroll
            for (int nt = 0; nt < 4; nt++)
                acc[mt][nt] = __builtin_amdgcn_mfma_f32_16x16x32_bf16(af[mt], bfr_[nt], acc[mt][nt], 0, 0, 0);
    }

    if (z == 2) {
        const int b = m0 >> 11, t0 = m0 & 2047;
        float bvv[4];
        #pragma unroll
        for (int nt = 0; nt < 4; nt++) bvv[nt] = bias[n0 + wn + nt * 16 + ln];
        #pragma unroll
        for (int ph = 0; ph < 4; ph++) {
            const int mh = ph >> 1, nh = ph & 1;
            __syncthreads();
            if ((wave >> 1) == mh && (wave & 1) == nh) {
                #pragma unroll
                for (int mt = 0; mt < 4; mt++)
                    #pragma unroll
                    for (int nt = 0; nt < 4; nt++) {
                        int2 pk;
                        pk.x = (int)pack2_rn(acc[mt][nt][0] + bvv[nt], acc[mt][nt][1] + bvv[nt]);
                        pk.y = (int)pack2_rn(acc[mt][nt][2] + bvv[nt], acc[mt][nt][3] + bvv[nt]);
                        *(int2*)(TR + (nt * 16 + ln) * 72 + mt * 16 + hi * 4) = pk;
                    }
            }
            __syncthreads();
            const int chl = tid >> 2, seg = tid & 3;
            const s8v r0 = *(const s8v*)(TR + chl * 72 + seg * 16);
            const s8v r1 = *(const s8v*)(TR + chl * 72 + seg * 16 + 8);
            short* dst = Vto + (size_t)(b * 1024 + n0 + nh * 64 + chl) * Tsz + t0 + mh * 64 + seg * 16;
            *(s8v*)(dst) = r0;
            *(s8v*)(dst + 8) = r1;
        }
        return;
    }

    const float scale = (z == 0) ? QSCALE : 1.0f;
    short* out = (z == 0) ? Qo : Ko;

    #pragma unroll
    for (int nt = 0; nt < 4; nt++) {
        const int col = n0 + wn + nt * 16 + ln;
        const float bvv = bias[col];
        #pragma unroll
        for (int mt = 0; mt < 4; mt++) {
            const int row0 = m0 + wm + mt * 16 + hi * 4;
            #pragma unroll
            for (int i = 0; i < 4; i++)
                out[(size_t)(row0 + i) * Csz + col] = (short)bfr((acc[mt][nt][i] + bvv) * scale);
        }
    }
}

// ---------------- output projection GEMM (f32 out; round-9 version) ----------------
__global__ __launch_bounds__(256, 2) void proj_gemm(
    const short* __restrict__ A, const short* __restrict__ W,
    const float* __restrict__ bias, float* __restrict__ out)
{
    __shared__ __align__(16) short Ash[128 * 32];
    __shared__ __align__(16) short Bsh[64 * 32];

    const int tid = threadIdx.x, lane = tid & 63, wave = tid >> 6;
    const int ln = lane & 15, hi = lane >> 4;
    const int m0 = blockIdx.x * 128, n0 = blockIdx.y * 64;
    const int wm = (wave >> 1) * 64, wn = (wave & 1) * 32;

    const short* Ag = A + (size_t)(m0 + (tid >> 2)) * Csz + (tid & 3) * 8;
    const short* Bg = W + (size_t)(n0 + (tid >> 2)) * Csz + (tid & 3) * 8;

    f4v acc[4][2];
    #pragma unroll
    for (int mt = 0; mt < 4; mt++)
        #pragma unroll
        for (int nt = 0; nt < 2; nt++)
            #pragma unroll
            for (int i = 0; i < 4; i++) acc[mt][nt][i] = 0.f;

    for (int k0 = 0; k0 < Csz; k0 += 32) {
        __syncthreads();
        gload_lds(Ag + k0, Ash + tid * 8);
        gload_lds(Ag + k0 + (size_t)64 * Csz, Ash + 2048 + tid * 8);
        gload_lds(Bg + k0, Bsh + tid * 8);
        __syncthreads();

        s8v af[4], bfr_[2];
        #pragma unroll
        for (int mt = 0; mt < 4; mt++)
            af[mt] = *(const s8v*)(Ash + (wm + mt * 16 + ln) * 32 + hi * 8);
        #pragma unroll
        for (int nt = 0; nt < 2; nt++)
            bfr_[nt] = *(const s8v*)(Bsh + (wn + nt * 16 + ln) * 32 + hi * 8);
        #pragma unroll
        for (int mt = 0; mt < 4; mt++)
            #pragma unroll
            for (int nt = 0; nt < 2; nt++)
                acc[mt][nt] = __builtin_amdgcn_mfma_f32_16x16x32_bf16(af[mt], bfr_[nt], acc[mt][nt], 0, 0, 0);
    }

    #pragma unroll
    for (int nt = 0; nt < 2; nt++) {
        const int col = n0 + wn + nt * 16 + ln;
        const float bvv = bias[col];
        #pragma unroll
        for (int mt = 0; mt < 4; mt++)
            #pragma unroll
            for (int i = 0; i < 4; i++)
                out[(size_t)(m0 + wm + mt * 16 + hi * 4 + i) * Csz + col] = acc[mt][nt][i] + bvv;
    }
}

// ---------------- Flash attention v21: v17 structure + XCD-affinity decode (NO setprio) ----------------
// Round-13 crash post-mortem: setprio was the only exotic addition; removed.
// Single change vs v17 (42.1us green): block decode gives all 16 same-bh blocks
// the same blockIdx%8 -> one XCD -> per-bh 1MB K/V stream fits the 4MB XCD L2.
// Decode (bijective; verified): x=n&7, m=n>>3, bh=((m&3)<<3)|x, rest=m>>2,
// j=rest>>3, ti=rest&7, t=j?15-ti:ti. Pair (n, n+256): m+32 -> m&3 unchanged
// (bh same), rest+8 -> j flips (complementary t) — v17's pairing preserved.
__global__ __launch_bounds__(256, 2) void attn21(
    const short* __restrict__ Q, const short* __restrict__ Kg,
    const short* __restrict__ Vt, short* __restrict__ Y)
{
    __shared__ __align__(16) short SB[2][2][64 * 64];   // [buf][K/V][row][swizzled 16B slots]

    const int tid = threadIdx.x, lane = tid & 63, wave = tid >> 6;
    const int ln = lane & 15, hi = lane >> 4;

    // XCD-affinity decode
    const int n = blockIdx.x;
    const int x = n & 7, m = n >> 3;
    const int bh = ((m & 3) << 3) | x;                // 0..31, same-bh -> same XCD slot
    const int rest = m >> 2;                          // 0..15
    const int j = rest >> 3, ti = rest & 7;
    const int t = j ? (15 - ti) : ti;                 // 0..15
    const int qts_[2] = { t, 31 - t };                // light, heavy
    const int nkb = 32 - t;                           // key-tiles (heavy's need)

    const size_t base = (size_t)(bh >> 4) * Tsz * Csz + (size_t)(bh & 15) * 64;
    const size_t vtbase = (size_t)bh * 64 * Tsz;
    const int qrel = wave * 16 + ln;                  // within-tile q row (MFMA n-col)

    s8v qf[2][2];
    #pragma unroll
    for (int tt = 0; tt < 2; tt++)
        #pragma unroll
        for (int kk = 0; kk < 2; kk++)
            qf[tt][kk] = *(const s8v*)(Q + base + (size_t)(qts_[tt] * 64 + qrel) * Csz + kk * 32 + hi * 8);

    f4v o[2][4];
    f4v lacc[2];
    #pragma unroll
    for (int tt = 0; tt < 2; tt++) {
        #pragma unroll
        for (int i = 0; i < 4; i++) lacc[tt][i] = 0.f;
        #pragma unroll
        for (int dt = 0; dt < 4; dt++)
            #pragma unroll
            for (int i = 0; i < 4; i++) o[tt][dt][i] = 0.f;
    }

    const s8v ones8 = { (short)0x3F80, (short)0x3F80, (short)0x3F80, (short)0x3F80,
                        (short)0x3F80, (short)0x3F80, (short)0x3F80, (short)0x3F80 };

    const int sr = tid >> 3, scs = tid & 7;
    const int csw = (scs ^ (sr & 7)) * 8;             // pre-swizzled col offset (shorts)
    const short* KsA = Kg + base + (size_t)sr * Csz + csw;
    const short* KsB = KsA + (size_t)32 * Csz;
    const short* VsA = Vt + vtbase + (size_t)sr * Tsz + csw;
    const short* VsB = VsA + (size_t)32 * Tsz;

    int foff[2][4];
    #pragma unroll
    for (int nt = 0; nt < 4; nt++)
        #pragma unroll
        for (int kk = 0; kk < 2; kk++)
            foff[kk][nt] = (nt * 16 + ln) * 64 + (((kk * 4 + hi) ^ (ln & 7)) * 8);

    #define STAGE(B, kb_) {                                      \
        const size_t ko_ = (size_t)(kb_) * 64;                   \
        gload_lds(KsA + ko_ * Csz, &SB[B][0][tid * 8]);          \
        gload_lds(KsB + ko_ * Csz, &SB[B][0][2048 + tid * 8]);   \
        gload_lds(VsA + ko_,       &SB[B][1][tid * 8]);          \
        gload_lds(VsB + ko_,       &SB[B][1][2048 + tid * 8]);   \
    }

    STAGE(0, 0);
    asm volatile("s_waitcnt vmcnt(0)" ::: "memory");
    __builtin_amdgcn_s_barrier();

    #define TILE(B0, B1, kb_) {                                                     \
        const bool st_ = (kb_) + 1 < nkb;                                           \
        if (st_) STAGE(B1, (kb_) + 1);                                              \
        s8v kf[2][4], vf[2][4];                                                     \
        for (int nt = 0; nt < 4; nt++) {                                            \
            kf[0][nt] = *(const s8v*)(&SB[B0][0][foff[0][nt]]);                     \
            kf[1][nt] = *(const s8v*)(&SB[B0][0][foff[1][nt]]);                     \
            vf[0][nt] = *(const s8v*)(&SB[B0][1][foff[0][nt]]);                     \
            vf[1][nt] = *(const s8v*)(&SB[B0][1][foff[1][nt]]);                     \
        }                                                                           \
        _Pragma("unroll")                                                           \
        for (int tt = 0; tt < 2; tt++) {                                            \
            if ((kb_) > qts_[tt]) continue;          /* wave-uniform */             \
            f4v s[4];                                                               \
            for (int nt = 0; nt < 4; nt++) {                                        \
                for (int i = 0; i < 4; i++) s[nt][i] = 0.f;                         \
                s[nt] = __builtin_amdgcn_mfma_f32_16x16x32_bf16(kf[0][nt], qf[tt][0], s[nt], 0, 0, 0); \
                s[nt] = __builtin_amdgcn_mfma_f32_16x16x32_bf16(kf[1][nt], qf[tt][1], s[nt], 0, 0, 0); \
            }                                                                       \
            const bool dg_ = ((kb_) == qts_[tt]);                                   \
            unsigned pw[4][2];                                                      \
            for (int nt = 0; nt < 4; nt++) {                                        \
                float e0 = exp2f(s[nt][0]), e1 = exp2f(s[nt][1]);                   \
                float e2 = exp2f(s[nt][2]), e3 = exp2f(s[nt][3]);                   \
                if (dg_) {                                                          \
                    const int kr = nt * 16 + hi * 4;                                \
                    if (kr + 0 > qrel) e0 = 0.f;                                    \
                    if (kr + 1 > qrel) e1 = 0.f;                                    \
                    if (kr + 2 > qrel) e2 = 0.f;                                    \
                    if (kr + 3 > qrel) e3 = 0.f;                                    \
                }                                                                   \
                pw[nt][0] = cvt2(e0, e1);                                           \
                pw[nt][1] = cvt2(e2, e3);                                           \
            }                                                                       \
            u2v r0a = __builtin_amdgcn_permlane32_swap(pw[0][0], pw[1][0], false, false); \
            u2v r0b = __builtin_amdgcn_permlane16_swap(r0a[0], r0a[1], false, false); \
            u2v r1a = __builtin_amdgcn_permlane32_swap(pw[0][1], pw[1][1], false, false); \
            u2v r1b = __builtin_amdgcn_permlane16_swap(r1a[0], r1a[1], false, false); \
            u2v r2a = __builtin_amdgcn_permlane32_swap(pw[2][0], pw[3][0], false, false); \
            u2v r2b = __builtin_amdgcn_permlane16_swap(r2a[0], r2a[1], false, false); \
            u2v r3a = __builtin_amdgcn_permlane32_swap(pw[2][1], pw[3][1], false, false); \
            u2v r3b = __builtin_amdgcn_permlane16_swap(r3a[0], r3a[1], false, false); \
            i4v p0 = { (int)r0b[0], (int)r1b[0], (int)r0b[1], (int)r1b[1] };        \
            i4v p1 = { (int)r2b[0], (int)r3b[0], (int)r2b[1], (int)r3b[1] };        \
            const s8v pb0 = __builtin_bit_cast(s8v, p0);                            \
            const s8v pb1 = __builtin_bit_cast(s8v, p1);                            \
            for (int dt = 0; dt < 4; dt++) {                                        \
                o[tt][dt] = __builtin_amdgcn_mfma_f32_16x16x32_bf16(vf[0][dt], pb0, o[tt][dt], 0, 0, 0); \
                o[tt][dt] = __builtin_amdgcn_mfma_f32_16x16x32_bf16(vf[1][dt], pb1, o[tt][dt], 0, 0, 0); \
            }                                                                       \
            lacc[tt] = __builtin_amdgcn_mfma_f32_16x16x32_bf16(ones8, pb0, lacc[tt], 0, 0, 0); \
            lacc[tt] = __builtin_amdgcn_mfma_f32_16x16x32_bf16(ones8, pb1, lacc[tt], 0, 0, 0); \
        }                                                                           \
        if (st_) {                                                                  \
            asm volatile("s_waitcnt vmcnt(0)" ::: "memory");                        \
            __builtin_amdgcn_s_barrier();                                           \
        }                                                                           \
    }

    for (int kb = 0; kb < nkb; kb += 2) {
        TILE(0, 1, kb);
        if (kb + 1 < nkb) TILE(1, 0, kb + 1);
    }
    #undef TILE
    #undef STAGE

    #pragma unroll
    for (int tt = 0; tt < 2; tt++) {
        const float inv = 1.0f / lacc[tt][0];
        const int qrow = qts_[tt] * 64 + qrel;
        #pragma unroll
        for (int dt = 0; dt < 4; dt++) {
            int2 w;
            w.x = (int)cvt2(o[tt][dt][0] * inv, o[tt][dt][1] * inv);
            w.y = (int)cvt2(o[tt][dt][2] * inv, o[tt][dt][3] * inv);
            *(int2*)(Y + base + (size_t)qrow * Csz + dt * 16 + hi * 4) = w;
        }
    }
}

extern "C" void kernel_launch(void* const* d_in, const int* in_sizes, int n_in,
                              void* d_out, int out_size, void* d_ws, size_t ws_size,
                              hipStream_t stream) {
    const float* x  = (const float*)d_in[0];
    const float* Wq = (const float*)d_in[1];
    const float* bq = (const float*)d_in[2];
    const float* Wk = (const float*)d_in[3];
    const float* bk = (const float*)d_in[4];
    const float* Wv = (const float*)d_in[5];
    const float* bv = (const float*)d_in[6];
    const float* Wp = (const float*)d_in[7];
    const float* bp = (const float*)d_in[8];

    char* ws = (char*)d_ws;
    short* Xb  = (short*)(ws);                 // 8 MB
    short* Wqb = (short*)(ws + (8u  << 20));   // 2 MB each
    short* Wkb = (short*)(ws + (10u << 20));
    short* Wvb = (short*)(ws + (12u << 20));
    short* Wpb = (short*)(ws + (14u << 20));
    short* Qb  = (short*)(ws + (16u << 20));   // 8 MB each
    short* Kb  = (short*)(ws + (24u << 20));
    short* Vtb = (short*)(ws + (32u << 20));   // V transposed per head [B*H*64, T]
    short* Yb  = (short*)(ws + (40u << 20));

    hipLaunchKernelGGL(cvt6, dim3(8192), dim3(256), 0, stream,
                       x, Wq, Wk, Wv, Wp, Xb, Wqb, Wkb, Wvb, Wpb);

    hipLaunchKernelGGL(qkv_gemm, dim3(32, 8, 3), dim3(256), 0, stream,
                       Xb, Wqb, Wkb, Wvb, bq, bk, bv, Qb, Kb, Vtb);

    hipLaunchKernelGGL(attn21, dim3(512), dim3(256), 0, stream, Qb, Kb, Vtb, Yb);

    hipLaunchKernelGGL(proj_gemm, dim3(32, 16), dim3(256), 0, stream, Yb, Wpb, bp, (float*)d_out);
}

// Round 15
// 177.949 us; speedup vs baseline: 1.0850x; 1.0163x over previous
//
#include <hip/hip_runtime.h>
#include <hip/hip_bf16.h>

#define Tsz 2048
#define Csz 1024
#define Hn 16

typedef short s8v __attribute__((ext_vector_type(8)));
typedef short s4v __attribute__((ext_vector_type(4)));
typedef float f4v __attribute__((ext_vector_type(4)));
typedef int   i4v __attribute__((ext_vector_type(4)));
typedef unsigned u2v __attribute__((ext_vector_type(2)));

#define QSCALE (0.125f * 1.44269504088896f)  // 1/sqrt(64) * log2(e), folded into Q

// fast bf16 round (bits+0x8000)>>16 : 2 VALU vs ~6 for software RNE
__device__ __forceinline__ unsigned short bfr(float x) {
    return (unsigned short)((__builtin_bit_cast(unsigned, x) + 0x8000u) >> 16);
}
__device__ __forceinline__ unsigned pack2_rn(float a, float b) {
    const unsigned ua = __builtin_bit_cast(unsigned, a) + 0x8000u;
    const unsigned ub = __builtin_bit_cast(unsigned, b) + 0x8000u;
    return (ua >> 16) | (ub & 0xFFFF0000u);
}
// v_cvt_pk_bf16_f32 via HIP conversion (compiler emits the packed cvt; a->low, b->high)
// NOTE: __hip_bfloat162 is not trivially copyable in this ROCm -> memcpy, not bit_cast.
__device__ __forceinline__ unsigned cvt2(float a, float b) {
    __hip_bfloat162 h = __float22bfloat162_rn(float2{a, b});
    unsigned r;
    __builtin_memcpy(&r, &h, 4);
    return r;
}

__device__ __forceinline__ void gload_lds(const void* g, void* l) {
    __builtin_amdgcn_global_load_lds(
        (const __attribute__((address_space(1))) void*)g,
        (__attribute__((address_space(3))) void*)l, 16, 0, 0);
}

// ---------------- fp32 -> bf16 conversion, exact-size grid (8192 blocks) ----------------
__global__ void cvt6(const float* __restrict__ x, const float* __restrict__ wq,
                     const float* __restrict__ wk, const float* __restrict__ wv,
                     const float* __restrict__ wp,
                     short* __restrict__ xo, short* __restrict__ qo,
                     short* __restrict__ ko, short* __restrict__ vo,
                     short* __restrict__ po) {
    const int bx = blockIdx.x;
    const float* in; short* out; int ib;
    if (bx < 4096) { in = x; out = xo; ib = bx; }
    else {
        const int r = bx - 4096, w = r >> 10;
        ib = r & 1023;
        switch (w) {
            case 0: in = wq; out = qo; break;
            case 1: in = wk; out = ko; break;
            case 2: in = wv; out = vo; break;
            default: in = wp; out = po; break;
        }
    }
    const int i = ib * 1024 + threadIdx.x * 4;
    float4 v = *(const float4*)(in + i);
    int2 o;
    o.x = (int)pack2_rn(v.x, v.y);
    o.y = (int)pack2_rn(v.z, v.w);
    *(int2*)(out + i) = o;
}

// ---------------- fused QKV GEMM (m97 structure; round-9 version) ----------------
__global__ __launch_bounds__(256, 3) void qkv_gemm(
    const short* __restrict__ X,
    const short* __restrict__ Wq, const short* __restrict__ Wk, const short* __restrict__ Wv,
    const float* __restrict__ bq, const float* __restrict__ bk, const float* __restrict__ bv,
    short* __restrict__ Qo, short* __restrict__ Ko, short* __restrict__ Vto)
{
    const int z = blockIdx.z;
    const short* W = (z == 0) ? Wq : (z == 1) ? Wk : Wv;
    const float* bias = (z == 0) ? bq : (z == 1) ? bk : bv;

    __shared__ __align__(16) short Ash[128 * 32];
    __shared__ __align__(16) short Bsh[128 * 32];
    __shared__ __align__(16) short TR[64 * 72];   // transpose staging (z==2 epilogue)

    const int tid = threadIdx.x, lane = tid & 63, wave = tid >> 6;
    const int ln = lane & 15, hi = lane >> 4;
    const int m0 = blockIdx.x * 128, n0 = blockIdx.y * 128;
    const int wm = (wave >> 1) * 64, wn = (wave & 1) * 64;

    const short* Ag = X + (size_t)(m0 + (tid >> 2)) * Csz + (tid & 3) * 8;
    const short* Bg = W + (size_t)(n0 + (tid >> 2)) * Csz + (tid & 3) * 8;

    f4v acc[4][4];
    #pragma unroll
    for (int mt = 0; mt < 4; mt++)
        #pragma unroll
        for (int nt = 0; nt < 4; nt++)
            #pragma unroll
            for (int i = 0; i < 4; i++) acc[mt][nt][i] = 0.f;

    for (int k0 = 0; k0 < Csz; k0 += 32) {
        __syncthreads();
        gload_lds(Ag + k0, Ash + tid * 8);
        gload_lds(Ag + k0 + (size_t)64 * Csz, Ash + 2048 + tid * 8);
        gload_lds(Bg + k0, Bsh + tid * 8);
        gload_lds(Bg + k0 + (size_t)64 * Csz, Bsh + 2048 + tid * 8);
        __syncthreads();

        s8v af[4], bfr_[4];
        #pragma unroll
        for (int mt = 0; mt < 4; mt++)
            af[mt] = *(const s8v*)(Ash + (wm + mt * 16 + ln) * 32 + hi * 8);
        #pragma unroll
        for (int nt = 0; nt < 4; nt++)
            bfr_[nt] = *(const s8v*)(Bsh + (wn + nt * 16 + ln) * 32 + hi * 8);
        #pragma unroll
        for (int mt = 0; mt < 4; mt++)
            #pragma unroll
            for (int nt = 0; nt < 4; nt++)
                acc[mt][nt] = __builtin_amdgcn_mfma_f32_16x16x32_bf16(af[mt], bfr_[nt], acc[mt][nt], 0, 0, 0);
    }

    if (z == 2) {
        const int b = m0 >> 11, t0 = m0 & 2047;
        float bvv[4];
        #pragma unroll
        for (int nt = 0; nt < 4; nt++) bvv[nt] = bias[n0 + wn + nt * 16 + ln];
        #pragma unroll
        for (int ph = 0; ph < 4; ph++) {
            const int mh = ph >> 1, nh = ph & 1;
            __syncthreads();
            if ((wave >> 1) == mh && (wave & 1) == nh) {
                #pragma unroll
                for (int mt = 0; mt < 4; mt++)
                    #pragma unroll
                    for (int nt = 0; nt < 4; nt++) {
                        int2 pk;
                        pk.x = (int)pack2_rn(acc[mt][nt][0] + bvv[nt], acc[mt][nt][1] + bvv[nt]);
                        pk.y = (int)pack2_rn(acc[mt][nt][2] + bvv[nt], acc[mt][nt][3] + bvv[nt]);
                        *(int2*)(TR + (nt * 16 + ln) * 72 + mt * 16 + hi * 4) = pk;
                    }
            }
            __syncthreads();
            const int chl = tid >> 2, seg = tid & 3;
            const s8v r0 = *(const s8v*)(TR + chl * 72 + seg * 16);
            const s8v r1 = *(const s8v*)(TR + chl * 72 + seg * 16 + 8);
            short* dst = Vto + (size_t)(b * 1024 + n0 + nh * 64 + chl) * Tsz + t0 + mh * 64 + seg * 16;
            *(s8v*)(dst) = r0;
            *(s8v*)(dst + 8) = r1;
        }
        return;
    }

    const float scale = (z == 0) ? QSCALE : 1.0f;
    short* out = (z == 0) ? Qo : Ko;

    #pragma unroll
    for (int nt = 0; nt < 4; nt++) {
        const int col = n0 + wn + nt * 16 + ln;
        const float bvv = bias[col];
        #pragma unroll
        for (int mt = 0; mt < 4; mt++) {
            const int row0 = m0 + wm + mt * 16 + hi * 4;
            #pragma unroll
            for (int i = 0; i < 4; i++)
                out[(size_t)(row0 + i) * Csz + col] = (short)bfr((acc[mt][nt][i] + bvv) * scale);
        }
    }
}

// ---------------- output projection GEMM (f32 out; round-9 version) ----------------
__global__ __launch_bounds__(256, 2) void proj_gemm(
    const short* __restrict__ A, const short* __restrict__ W,
    const float* __restrict__ bias, float* __restrict__ out)
{
    __shared__ __align__(16) short Ash[128 * 32];
    __shared__ __align__(16) short Bsh[64 * 32];

    const int tid = threadIdx.x, lane = tid & 63, wave = tid >> 6;
    const int ln = lane & 15, hi = lane >> 4;
    const int m0 = blockIdx.x * 128, n0 = blockIdx.y * 64;
    const int wm = (wave >> 1) * 64, wn = (wave & 1) * 32;

    const short* Ag = A + (size_t)(m0 + (tid >> 2)) * Csz + (tid & 3) * 8;
    const short* Bg = W + (size_t)(n0 + (tid >> 2)) * Csz + (tid & 3) * 8;

    f4v acc[4][2];
    #pragma unroll
    for (int mt = 0; mt < 4; mt++)
        #pragma unroll
        for (int nt = 0; nt < 2; nt++)
            #pragma unroll
            for (int i = 0; i < 4; i++) acc[mt][nt][i] = 0.f;

    for (int k0 = 0; k0 < Csz; k0 += 32) {
        __syncthreads();
        gload_lds(Ag + k0, Ash + tid * 8);
        gload_lds(Ag + k0 + (size_t)64 * Csz, Ash + 2048 + tid * 8);
        gload_lds(Bg + k0, Bsh + tid * 8);
        __syncthreads();

        s8v af[4], bfr_[2];
        #pragma unroll
        for (int mt = 0; mt < 4; mt++)
            af[mt] = *(const s8v*)(Ash + (wm + mt * 16 + ln) * 32 + hi * 8);
        #pragma unroll
        for (int nt = 0; nt < 2; nt++)
            bfr_[nt] = *(const s8v*)(Bsh + (wn + nt * 16 + ln) * 32 + hi * 8);
        #pragma unroll
        for (int mt = 0; mt < 4; mt++)
            #pragma unroll
            for (int nt = 0; nt < 2; nt++)
                acc[mt][nt] = __builtin_amdgcn_mfma_f32_16x16x32_bf16(af[mt], bfr_[nt], acc[mt][nt], 0, 0, 0);
    }

    #pragma unroll
    for (int nt = 0; nt < 2; nt++) {
        const int col = n0 + wn + nt * 16 + ln;
        const float bvv = bias[col];
        #pragma unroll
        for (int mt = 0; mt < 4; mt++)
            #pragma unroll
            for (int i = 0; i < 4; i++)
                out[(size_t)(m0 + wm + mt * 16 + hi * 4 + i) * Csz + col] = acc[mt][nt][i] + bvv;
    }
}

// ---------------- Flash attention v17 (best measured: 42.1 us, round 9) ----------------
// 512 blocks x 256 thr; block handles q-tiles {t, 31-t} sharing ONE K/V stream.
// Default blockIdx decode (XCD-affinity tested null at this occupancy, round 14).
// Core: zero-conflict XOR-swizzled K/V via pre-swizzled gload_lds source,
// in-register P redistribution (permlane32/16 swap builtins), MFMA l-sum,
// packed bf16 cvt. Depth-1 prefetch, one vmcnt(0)+barrier per key-tile;
// co-resident pair (n, n+256) runs anti-phase to cover each other's stalls.
__global__ __launch_bounds__(256, 2) void attn17(
    const short* __restrict__ Q, const short* __restrict__ Kg,
    const short* __restrict__ Vt, short* __restrict__ Y)
{
    __shared__ __align__(16) short SB[2][2][64 * 64];   // [buf][K/V][row][swizzled 16B slots]

    const int tid = threadIdx.x, lane = tid & 63, wave = tid >> 6;
    const int ln = lane & 15, hi = lane >> 4;

    const int n = blockIdx.x;
    const int j = n >> 8, n0 = n & 255;
    const int bh = n0 >> 3, ti = n0 & 7;
    const int t = j ? (15 - ti) : ti;                 // 0..15
    const int qts_[2] = { t, 31 - t };                // light, heavy
    const int nkb = 32 - t;                           // key-tiles (heavy's need)

    const size_t base = (size_t)(bh >> 4) * Tsz * Csz + (size_t)(bh & 15) * 64;
    const size_t vtbase = (size_t)bh * 64 * Tsz;
    const int qrel = wave * 16 + ln;                  // within-tile q row (MFMA n-col)

    s8v qf[2][2];
    #pragma unroll
    for (int tt = 0; tt < 2; tt++)
        #pragma unroll
        for (int kk = 0; kk < 2; kk++)
            qf[tt][kk] = *(const s8v*)(Q + base + (size_t)(qts_[tt] * 64 + qrel) * Csz + kk * 32 + hi * 8);

    f4v o[2][4];
    f4v lacc[2];
    #pragma unroll
    for (int tt = 0; tt < 2; tt++) {
        #pragma unroll
        for (int i = 0; i < 4; i++) lacc[tt][i] = 0.f;
        #pragma unroll
        for (int dt = 0; dt < 4; dt++)
            #pragma unroll
            for (int i = 0; i < 4; i++) o[tt][dt][i] = 0.f;
    }

    const s8v ones8 = { (short)0x3F80, (short)0x3F80, (short)0x3F80, (short)0x3F80,
                        (short)0x3F80, (short)0x3F80, (short)0x3F80, (short)0x3F80 };

    const int sr = tid >> 3, scs = tid & 7;
    const int csw = (scs ^ (sr & 7)) * 8;             // pre-swizzled col offset (shorts)
    const short* KsA = Kg + base + (size_t)sr * Csz + csw;
    const short* KsB = KsA + (size_t)32 * Csz;
    const short* VsA = Vt + vtbase + (size_t)sr * Tsz + csw;
    const short* VsB = VsA + (size_t)32 * Tsz;

    int foff[2][4];
    #pragma unroll
    for (int nt = 0; nt < 4; nt++)
        #pragma unroll
        for (int kk = 0; kk < 2; kk++)
            foff[kk][nt] = (nt * 16 + ln) * 64 + (((kk * 4 + hi) ^ (ln & 7)) * 8);

    #define STAGE(B, kb_) {                                      \
        const size_t ko_ = (size_t)(kb_) * 64;                   \
        gload_lds(KsA + ko_ * Csz, &SB[B][0][tid * 8]);          \
        gload_lds(KsB + ko_ * Csz, &SB[B][0][2048 + tid * 8]);   \
        gload_lds(VsA + ko_,       &SB[B][1][tid * 8]);          \
        gload_lds(VsB + ko_,       &SB[B][1][2048 + tid * 8]);   \
    }

    STAGE(0, 0);
    asm volatile("s_waitcnt vmcnt(0)" ::: "memory");
    __builtin_amdgcn_s_barrier();

    #define TILE(B0, B1, kb_) {                                                     \
        const bool st_ = (kb_) + 1 < nkb;                                           \
        if (st_) STAGE(B1, (kb_) + 1);                                              \
        s8v kf[2][4], vf[2][4];                                                     \
        for (int nt = 0; nt < 4; nt++) {                                            \
            kf[0][nt] = *(const s8v*)(&SB[B0][0][foff[0][nt]]);                     \
            kf[1][nt] = *(const s8v*)(&SB[B0][0][foff[1][nt]]);                     \
            vf[0][nt] = *(const s8v*)(&SB[B0][1][foff[0][nt]]);                     \
            vf[1][nt] = *(const s8v*)(&SB[B0][1][foff[1][nt]]);                     \
        }                                                                           \
        _Pragma("unroll")                                                           \
        for (int tt = 0; tt < 2; tt++) {                                            \
            if ((kb_) > qts_[tt]) continue;          /* wave-uniform */             \
            f4v s[4];                                                               \
            for (int nt = 0; nt < 4; nt++) {                                        \
                for (int i = 0; i < 4; i++) s[nt][i] = 0.f;                         \
                s[nt] = __builtin_amdgcn_mfma_f32_16x16x32_bf16(kf[0][nt], qf[tt][0], s[nt], 0, 0, 0); \
                s[nt] = __builtin_amdgcn_mfma_f32_16x16x32_bf16(kf[1][nt], qf[tt][1], s[nt], 0, 0, 0); \
            }                                                                       \
            const bool dg_ = ((kb_) == qts_[tt]);                                   \
            unsigned pw[4][2];                                                      \
            for (int nt = 0; nt < 4; nt++) {                                        \
                float e0 = exp2f(s[nt][0]), e1 = exp2f(s[nt][1]);                   \
                float e2 = exp2f(s[nt][2]), e3 = exp2f(s[nt][3]);                   \
                if (dg_) {                                                          \
                    const int kr = nt * 16 + hi * 4;                                \
                    if (kr + 0 > qrel) e0 = 0.f;                                    \
                    if (kr + 1 > qrel) e1 = 0.f;                                    \
                    if (kr + 2 > qrel) e2 = 0.f;                                    \
                    if (kr + 3 > qrel) e3 = 0.f;                                    \
                }                                                                   \
                pw[nt][0] = cvt2(e0, e1);                                           \
                pw[nt][1] = cvt2(e2, e3);                                           \
            }                                                                       \
            u2v r0a = __builtin_amdgcn_permlane32_swap(pw[0][0], pw[1][0], false, false); \
            u2v r0b = __builtin_amdgcn_permlane16_swap(r0a[0], r0a[1], false, false); \
            u2v r1a = __builtin_amdgcn_permlane32_swap(pw[0][1], pw[1][1], false, false); \
            u2v r1b = __builtin_amdgcn_permlane16_swap(r1a[0], r1a[1], false, false); \
            u2v r2a = __builtin_amdgcn_permlane32_swap(pw[2][0], pw[3][0], false, false); \
            u2v r2b = __builtin_amdgcn_permlane16_swap(r2a[0], r2a[1], false, false); \
            u2v r3a = __builtin_amdgcn_permlane32_swap(pw[2][1], pw[3][1], false, false); \
            u2v r3b = __builtin_amdgcn_permlane16_swap(r3a[0], r3a[1], false, false); \
            i4v p0 = { (int)r0b[0], (int)r1b[0], (int)r0b[1], (int)r1b[1] };        \
            i4v p1 = { (int)r2b[0], (int)r3b[0], (int)r2b[1], (int)r3b[1] };        \
            const s8v pb0 = __builtin_bit_cast(s8v, p0);                            \
            const s8v pb1 = __builtin_bit_cast(s8v, p1);                            \
            for (int dt = 0; dt < 4; dt++) {                                        \
                o[tt][dt] = __builtin_amdgcn_mfma_f32_16x16x32_bf16(vf[0][dt], pb0, o[tt][dt], 0, 0, 0); \
                o[tt][dt] = __builtin_amdgcn_mfma_f32_16x16x32_bf16(vf[1][dt], pb1, o[tt][dt], 0, 0, 0); \
            }                                                                       \
            lacc[tt] = __builtin_amdgcn_mfma_f32_16x16x32_bf16(ones8, pb0, lacc[tt], 0, 0, 0); \
            lacc[tt] = __builtin_amdgcn_mfma_f32_16x16x32_bf16(ones8, pb1, lacc[tt], 0, 0, 0); \
        }                                                                           \
        if (st_) {                                                                  \
            asm volatile("s_waitcnt vmcnt(0)" ::: "memory");                        \
            __builtin_amdgcn_s_barrier();                                           \
        }                                                                           \
    }

    for (int kb = 0; kb < nkb; kb += 2) {
        TILE(0, 1, kb);
        if (kb + 1 < nkb) TILE(1, 0, kb + 1);
    }
    #undef TILE
    #undef STAGE

    #pragma unroll
    for (int tt = 0; tt < 2; tt++) {
        const float inv = 1.0f / lacc[tt][0];
        const int qrow = qts_[tt] * 64 + qrel;
        #pragma unroll
        for (int dt = 0; dt < 4; dt++) {
            int2 w;
            w.x = (int)cvt2(o[tt][dt][0] * inv, o[tt][dt][1] * inv);
            w.y = (int)cvt2(o[tt][dt][2] * inv, o[tt][dt][3] * inv);
            *(int2*)(Y + base + (size_t)qrow * Csz + dt * 16 + hi * 4) = w;
        }
    }
}

extern "C" void kernel_launch(void* const* d_in, const int* in_sizes, int n_in,
                              void* d_out, int out_size, void* d_ws, size_t ws_size,
                              hipStream_t stream) {
    const float* x  = (const float*)d_in[0];
    const float* Wq = (const float*)d_in[1];
    const float* bq = (const float*)d_in[2];
    const float* Wk = (const float*)d_in[3];
    const float* bk = (const float*)d_in[4];
    const float* Wv = (const float*)d_in[5];
    const float* bv = (const float*)d_in[6];
    const float* Wp = (const float*)d_in[7];
    const float* bp = (const float*)d_in[8];

    char* ws = (char*)d_ws;
    short* Xb  = (short*)(ws);                 // 8 MB
    short* Wqb = (short*)(ws + (8u  << 20));   // 2 MB each
    short* Wkb = (short*)(ws + (10u << 20));
    short* Wvb = (short*)(ws + (12u << 20));
    short* Wpb = (short*)(ws + (14u << 20));
    short* Qb  = (short*)(ws + (16u << 20));   // 8 MB each
    short* Kb  = (short*)(ws + (24u << 20));
    short* Vtb = (short*)(ws + (32u << 20));   // V transposed per head [B*H*64, T]
    short* Yb  = (short*)(ws + (40u << 20));

    hipLaunchKernelGGL(cvt6, dim3(8192), dim3(256), 0, stream,
                       x, Wq, Wk, Wv, Wp, Xb, Wqb, Wkb, Wvb, Wpb);

    hipLaunchKernelGGL(qkv_gemm, dim3(32, 8, 3), dim3(256), 0, stream,
                       Xb, Wqb, Wkb, Wvb, bq, bk, bv, Qb, Kb, Vtb);

    hipLaunchKernelGGL(attn17, dim3(512), dim3(256), 0, stream, Qb, Kb, Vtb, Yb);

    hipLaunchKernelGGL(proj_gemm, dim3(32, 16), dim3(256), 0, stream, Yb, Wpb, bp, (float*)d_out);
}